// Round 1
// baseline (787.930 us; speedup 1.0000x reference)
//
#include <hip/hip_runtime.h>

// ---------------------------------------------------------------------------
// SpatialGNN: 2x GATConv (2 heads -> 1 head), mean-pool per graph, MLP.
// Strategy: build CSR (sorted by dst) once per launch, then atomic-free
// wave-per-node softmax-aggregation. fp32 GEMMs register-tiled.
// ---------------------------------------------------------------------------

#define LRELU(x) ((x) > 0.f ? (x) : 0.2f * (x))

// ---------------- CSR build ----------------

__global__ void hist_kernel(const int* __restrict__ ei, int* __restrict__ deg,
                            int E, int E2) {
  int e = blockIdx.x * 256 + threadIdx.x;
  if (e >= E2) return;
  int d = (e < E) ? ei[E + e] : (e - E);   // self-loop for e >= E
  atomicAdd(&deg[d], 1);
}

__global__ void scan1_kernel(const int* __restrict__ deg, int* __restrict__ off,
                             int* __restrict__ sums, int n) {
  __shared__ int s[256];
  int t = threadIdx.x;
  int base = blockIdx.x * 1024 + t * 4;
  int v0 = (base + 0 < n) ? deg[base + 0] : 0;
  int v1 = (base + 1 < n) ? deg[base + 1] : 0;
  int v2 = (base + 2 < n) ? deg[base + 2] : 0;
  int v3 = (base + 3 < n) ? deg[base + 3] : 0;
  int sum = v0 + v1 + v2 + v3;
  s[t] = sum;
  __syncthreads();
  for (int d = 1; d < 256; d <<= 1) {
    int x = (t >= d) ? s[t - d] : 0;
    __syncthreads();
    s[t] += x;
    __syncthreads();
  }
  if (t == 255) sums[blockIdx.x] = s[255];
  int run = s[t] - sum;  // exclusive prefix within chunk
  if (base + 0 < n) { off[base + 0] = run; run += v0; }
  if (base + 1 < n) { off[base + 1] = run; run += v1; }
  if (base + 2 < n) { off[base + 2] = run; run += v2; }
  if (base + 3 < n) { off[base + 3] = run; }
}

__global__ void scan2_kernel(int* __restrict__ sums, int nb) {
  __shared__ int s[256];
  int t = threadIdx.x;
  s[t] = (t < nb) ? sums[t] : 0;
  __syncthreads();
  if (t == 0) {
    int acc = 0;
    for (int i = 0; i < nb; ++i) { int v = s[i]; s[i] = acc; acc += v; }
  }
  __syncthreads();
  if (t < nb) sums[t] = s[t];
}

__global__ void scan3_kernel(int* __restrict__ off, const int* __restrict__ sums,
                             int n, int total) {
  int i = blockIdx.x * 256 + threadIdx.x;
  if (i < n) off[i] += sums[i >> 10];
  else if (i == n) off[n] = total;
}

__global__ void scatter_kernel(const int* __restrict__ ei, const int* __restrict__ off,
                               int* __restrict__ cnt2, int* __restrict__ ssrc,
                               int E, int E2) {
  int e = blockIdx.x * 256 + threadIdx.x;
  if (e >= E2) return;
  int s, d;
  if (e < E) { s = ei[e]; d = ei[E + e]; } else { s = d = e - E; }
  int p = off[d] + atomicAdd(&cnt2[d], 1);
  ssrc[p] = s;
}

// ---------------- fp32 GEMM: C[M x BN] = A[M x 128] * W[128 x BN] ----------------
// BM=64 rows/block, thread tile TM=4 x TN, K chunked by 32 through LDS.

template <int BN, int TN>
__global__ __launch_bounds__(256) void gemm_f32(const float* __restrict__ A,
                                                const float* __restrict__ W,
                                                float* __restrict__ C, int M) {
  constexpr int BM = 64, TM = 4, BK = 32;
  constexpr int TX = BN / TN;  // 16
  __shared__ float As[BK][BM];  // transposed A tile
  __shared__ float Ws[BK][BN];
  int tid = threadIdx.x;
  int tx = tid % TX;
  int ty = tid / TX;
  int row0 = blockIdx.x * BM;
  float acc[TM][TN] = {};
  for (int kb = 0; kb < 128; kb += BK) {
    for (int i = tid; i < BM * BK / 4; i += 256) {
      int r = i >> 3;      // BK/4 = 8 float4 per row
      int k4 = i & 7;
      float4 v = make_float4(0.f, 0.f, 0.f, 0.f);
      if (row0 + r < M)
        v = *reinterpret_cast<const float4*>(A + (size_t)(row0 + r) * 128 + kb + k4 * 4);
      As[k4 * 4 + 0][r] = v.x;
      As[k4 * 4 + 1][r] = v.y;
      As[k4 * 4 + 2][r] = v.z;
      As[k4 * 4 + 3][r] = v.w;
    }
    for (int i = tid; i < BK * BN / 4; i += 256) {
      reinterpret_cast<float4*>(&Ws[0][0])[i] =
          *reinterpret_cast<const float4*>(W + (size_t)kb * BN + i * 4);
    }
    __syncthreads();
#pragma unroll
    for (int k = 0; k < BK; ++k) {
      float a[TM], b[TN];
#pragma unroll
      for (int i = 0; i < TM; ++i) a[i] = As[k][ty * TM + i];
#pragma unroll
      for (int j = 0; j < TN; ++j) b[j] = Ws[k][tx * TN + j];
#pragma unroll
      for (int i = 0; i < TM; ++i)
#pragma unroll
        for (int j = 0; j < TN; ++j) acc[i][j] = fmaf(a[i], b[j], acc[i][j]);
    }
    __syncthreads();
  }
#pragma unroll
  for (int i = 0; i < TM; ++i) {
    int r = row0 + ty * TM + i;
    if (r < M) {
#pragma unroll
      for (int j = 0; j < TN; j += 4) {
        float4 v = make_float4(acc[i][j], acc[i][j + 1], acc[i][j + 2], acc[i][j + 3]);
        *reinterpret_cast<float4*>(C + (size_t)r * BN + tx * TN + j) = v;
      }
    }
  }
}

// ---------------- attention scores ----------------

// layer 1: h [N x 128] (2 heads x 64), a_src/a_dst [2 x 64]
__global__ void escore1_kernel(const float* __restrict__ h, const float* __restrict__ a_src,
                               const float* __restrict__ a_dst, float* __restrict__ es,
                               float* __restrict__ ed, int n) {
  int w = (blockIdx.x * 256 + threadIdx.x) >> 6;
  int lane = threadIdx.x & 63;
  if (w >= n) return;
  float v0 = h[(size_t)w * 128 + lane];
  float v1 = h[(size_t)w * 128 + 64 + lane];
  float s0 = v0 * a_src[lane];
  float s1 = v1 * a_src[64 + lane];
  float d0 = v0 * a_dst[lane];
  float d1 = v1 * a_dst[64 + lane];
  for (int o = 32; o; o >>= 1) {
    s0 += __shfl_down(s0, o);
    s1 += __shfl_down(s1, o);
    d0 += __shfl_down(d0, o);
    d1 += __shfl_down(d1, o);
  }
  if (lane == 0) {
    es[w * 2] = s0; es[w * 2 + 1] = s1;
    ed[w * 2] = d0; ed[w * 2 + 1] = d1;
  }
}

// layer 2: h [N x 64] (1 head), a_src/a_dst [1 x 64]
__global__ void escore2_kernel(const float* __restrict__ h, const float* __restrict__ a_src,
                               const float* __restrict__ a_dst, float* __restrict__ es,
                               float* __restrict__ ed, int n) {
  int w = (blockIdx.x * 256 + threadIdx.x) >> 6;
  int lane = threadIdx.x & 63;
  if (w >= n) return;
  float v = h[(size_t)w * 64 + lane];
  float s = v * a_src[lane];
  float d = v * a_dst[lane];
  for (int o = 32; o; o >>= 1) {
    s += __shfl_down(s, o);
    d += __shfl_down(d, o);
  }
  if (lane == 0) { es[w] = s; ed[w] = d; }
}

// ---------------- aggregation (wave per dst node, atomic-free) ----------------

__global__ void agg1_kernel(const float* __restrict__ h, const float* __restrict__ es,
                            const float* __restrict__ ed, const int* __restrict__ off,
                            const int* __restrict__ ssrc, const float* __restrict__ b,
                            float* __restrict__ out, int n) {
  int w = (blockIdx.x * 256 + threadIdx.x) >> 6;
  int lane = threadIdx.x & 63;
  if (w >= n) return;
  float ed0 = ed[w * 2], ed1 = ed[w * 2 + 1];
  float acc0 = 0.f, acc1 = 0.f, den0 = 0.f, den1 = 0.f;
  int e0 = off[w], e1 = off[w + 1];
  const float2* esv = reinterpret_cast<const float2*>(es);
  for (int e = e0; e < e1; ++e) {
    int s = ssrc[e];
    float2 ev = esv[s];
    float x0 = LRELU(ev.x + ed0);
    float x1 = LRELU(ev.y + ed1);
    float w0 = __expf(x0);
    float w1 = __expf(x1);
    den0 += w0; den1 += w1;
    acc0 = fmaf(w0, h[(size_t)s * 128 + lane], acc0);
    acc1 = fmaf(w1, h[(size_t)s * 128 + 64 + lane], acc1);
  }
  float o0 = acc0 / den0 + b[lane];
  float o1 = acc1 / den1 + b[64 + lane];
  out[(size_t)w * 128 + lane] = fmaxf(o0, 0.f);        // ReLU after layer 1
  out[(size_t)w * 128 + 64 + lane] = fmaxf(o1, 0.f);
}

__global__ void agg2_kernel(const float* __restrict__ h, const float* __restrict__ es,
                            const float* __restrict__ ed, const int* __restrict__ off,
                            const int* __restrict__ ssrc, const float* __restrict__ b,
                            float* __restrict__ out, int n) {
  int w = (blockIdx.x * 256 + threadIdx.x) >> 6;
  int lane = threadIdx.x & 63;
  if (w >= n) return;
  float edv = ed[w];
  float acc = 0.f, den = 0.f;
  int e0 = off[w], e1 = off[w + 1];
  for (int e = e0; e < e1; ++e) {
    int s = ssrc[e];
    float x = LRELU(es[s] + edv);
    float wgt = __expf(x);
    den += wgt;
    acc = fmaf(wgt, h[(size_t)s * 64 + lane], acc);
  }
  out[(size_t)w * 64 + lane] = acc / den + b[lane];    // no ReLU after layer 2
}

// ---------------- pooling + MLP ----------------

__global__ void pool_kernel(const float* __restrict__ x, const int* __restrict__ batch,
                            float* __restrict__ pooled, float* __restrict__ cnt, int n) {
  int w = (blockIdx.x * 256 + threadIdx.x) >> 6;
  int lane = threadIdx.x & 63;
  int n0 = w * 64;
  if (n0 >= n) return;
  int n1 = min(n, n0 + 64);
  float acc = 0.f;
  int cur = batch[n0];
  int run = 0;
  for (int i = n0; i < n1; ++i) {
    int g = batch[i];
    if (g != cur) {
      atomicAdd(&pooled[cur * 64 + lane], acc);
      if (lane == 0) atomicAdd(&cnt[cur], (float)run);
      acc = 0.f; run = 0; cur = g;
    }
    acc += x[(size_t)i * 64 + lane];
    ++run;
  }
  atomicAdd(&pooled[cur * 64 + lane], acc);
  if (lane == 0) atomicAdd(&cnt[cur], (float)run);
}

__global__ void mlp1_kernel(const float* __restrict__ pooled, const float* __restrict__ cnt,
                            const float* __restrict__ dw1, const float* __restrict__ db1,
                            float* __restrict__ z) {
  int g = blockIdx.x;
  int c = threadIdx.x;  // 64
  __shared__ float P[64];
  float inv = 1.0f / fmaxf(cnt[g], 1.0f);
  P[c] = pooled[g * 64 + c] * inv;
  __syncthreads();
  float s = db1[c];
#pragma unroll
  for (int k = 0; k < 64; ++k) s = fmaf(P[k], dw1[k * 64 + c], s);
  z[g * 64 + c] = fmaxf(s, 0.f);
}

__global__ void mlp2_kernel(const float* __restrict__ z, const float* __restrict__ dw2,
                            const float* __restrict__ db2, float* __restrict__ out) {
  int g = blockIdx.x;
  int o = threadIdx.x;  // 16
  __shared__ float Z[64];
  for (int i = o; i < 64; i += 16) Z[i] = z[g * 64 + i];
  __syncthreads();
  float s = db2[o];
#pragma unroll
  for (int c = 0; c < 64; ++c) s = fmaf(Z[c], dw2[c * 16 + o], s);
  out[g * 16 + o] = s;
}

// ---------------- launch ----------------

extern "C" void kernel_launch(void* const* d_in, const int* in_sizes, int n_in,
                              void* d_out, int out_size, void* d_ws, size_t ws_size,
                              hipStream_t stream) {
  const float* x      = (const float*)d_in[0];
  const int*   ei     = (const int*)d_in[1];
  const int*   batch  = (const int*)d_in[2];
  const float* W1     = (const float*)d_in[3];
  const float* a_src1 = (const float*)d_in[4];
  const float* a_dst1 = (const float*)d_in[5];
  const float* b1     = (const float*)d_in[6];
  const float* W2     = (const float*)d_in[7];
  const float* a_src2 = (const float*)d_in[8];
  const float* a_dst2 = (const float*)d_in[9];
  const float* b2     = (const float*)d_in[10];
  const float* dw1    = (const float*)d_in[11];
  const float* db1    = (const float*)d_in[12];
  const float* dw2    = (const float*)d_in[13];
  const float* db2    = (const float*)d_in[14];
  float* out = (float*)d_out;

  const int N = in_sizes[2];
  const int E = in_sizes[1] / 2;
  const int E2 = E + N;
  const int G = out_size / 16;

  char* ws = (char*)d_ws;
  size_t o = 0;
  auto alloc = [&](size_t bytes) {
    void* p = ws + o;
    o = (o + bytes + 255) & ~(size_t)255;
    return p;
  };
  int*   deg    = (int*)alloc((size_t)N * 4);
  int*   cnt2   = (int*)alloc((size_t)N * 4);
  int*   off    = (int*)alloc((size_t)(N + 1) * 4);
  int*   sums   = (int*)alloc(1024);
  int*   ssrc   = (int*)alloc((size_t)E2 * 4);
  float* es1    = (float*)alloc((size_t)N * 2 * 4);
  float* ed1    = (float*)alloc((size_t)N * 2 * 4);
  float* es2    = (float*)alloc((size_t)N * 4);
  float* ed2    = (float*)alloc((size_t)N * 4);
  float* pooled = (float*)alloc((size_t)G * 64 * 4);
  float* cntf   = (float*)alloc((size_t)G * 4);
  float* zbuf   = (float*)alloc((size_t)G * 64 * 4);
  float* bufA   = (float*)alloc((size_t)N * 128 * 4);  // h1, then h2
  float* bufB   = (float*)alloc((size_t)N * 128 * 4);  // out1, then out2

  hipMemsetAsync(deg, 0, (size_t)N * 4, stream);
  hipMemsetAsync(cnt2, 0, (size_t)N * 4, stream);
  hipMemsetAsync(pooled, 0, (size_t)G * 64 * 4, stream);
  hipMemsetAsync(cntf, 0, (size_t)G * 4, stream);

  int gE2 = (E2 + 255) / 256;
  hist_kernel<<<gE2, 256, 0, stream>>>(ei, deg, E, E2);
  int nb = (N + 1023) / 1024;
  scan1_kernel<<<nb, 256, 0, stream>>>(deg, off, sums, N);
  scan2_kernel<<<1, 256, 0, stream>>>(sums, nb);
  scan3_kernel<<<(N + 256) / 256, 256, 0, stream>>>(off, sums, N, E2);
  scatter_kernel<<<gE2, 256, 0, stream>>>(ei, off, cnt2, ssrc, E, E2);

  int gM = (N + 63) / 64;
  int gW = (N + 3) / 4;  // wave-per-node kernels, 4 waves/block

  // layer 1
  gemm_f32<128, 8><<<gM, 256, 0, stream>>>(x, W1, bufA, N);
  escore1_kernel<<<gW, 256, 0, stream>>>(bufA, a_src1, a_dst1, es1, ed1, N);
  agg1_kernel<<<gW, 256, 0, stream>>>(bufA, es1, ed1, off, ssrc, b1, bufB, N);

  // layer 2
  gemm_f32<64, 4><<<gM, 256, 0, stream>>>(bufB, W2, bufA, N);
  escore2_kernel<<<gW, 256, 0, stream>>>(bufA, a_src2, a_dst2, es2, ed2, N);
  agg2_kernel<<<gW, 256, 0, stream>>>(bufA, es2, ed2, off, ssrc, b2, bufB, N);

  // pool + MLP
  int nwPool = (N + 63) / 64;
  pool_kernel<<<(nwPool + 3) / 4, 256, 0, stream>>>(bufB, batch, pooled, cntf, N);
  mlp1_kernel<<<G, 64, 0, stream>>>(pooled, cntf, dw1, db1, zbuf);
  mlp2_kernel<<<G, 16, 0, stream>>>(zbuf, dw2, db2, out);
}

// Round 2
// 661.117 us; speedup vs baseline: 1.1918x; 1.1918x over previous
//
#include <hip/hip_runtime.h>

// ---------------------------------------------------------------------------
// SpatialGNN: 2x GATConv (2 heads -> 1 head), mean-pool per graph, MLP.
// CSR build once per launch -> atomic-free aggregation.
// R2: pre-normalized edge weights (wave-per-node, lane-parallel over edges),
//     float2 gathers in agg1, x4 unrolled edge loops for latency hiding.
// ---------------------------------------------------------------------------

#define LRELU(x) ((x) > 0.f ? (x) : 0.2f * (x))

// ---------------- CSR build ----------------

__global__ void hist_kernel(const int* __restrict__ ei, int* __restrict__ deg,
                            int E, int E2) {
  int e = blockIdx.x * 256 + threadIdx.x;
  if (e >= E2) return;
  int d = (e < E) ? ei[E + e] : (e - E);   // self-loop for e >= E
  atomicAdd(&deg[d], 1);
}

__global__ void scan1_kernel(const int* __restrict__ deg, int* __restrict__ off,
                             int* __restrict__ sums, int n) {
  __shared__ int s[256];
  int t = threadIdx.x;
  int base = blockIdx.x * 1024 + t * 4;
  int v0 = (base + 0 < n) ? deg[base + 0] : 0;
  int v1 = (base + 1 < n) ? deg[base + 1] : 0;
  int v2 = (base + 2 < n) ? deg[base + 2] : 0;
  int v3 = (base + 3 < n) ? deg[base + 3] : 0;
  int sum = v0 + v1 + v2 + v3;
  s[t] = sum;
  __syncthreads();
  for (int d = 1; d < 256; d <<= 1) {
    int x = (t >= d) ? s[t - d] : 0;
    __syncthreads();
    s[t] += x;
    __syncthreads();
  }
  if (t == 255) sums[blockIdx.x] = s[255];
  int run = s[t] - sum;  // exclusive prefix within chunk
  if (base + 0 < n) { off[base + 0] = run; run += v0; }
  if (base + 1 < n) { off[base + 1] = run; run += v1; }
  if (base + 2 < n) { off[base + 2] = run; run += v2; }
  if (base + 3 < n) { off[base + 3] = run; }
}

__global__ void scan2_kernel(int* __restrict__ sums, int nb) {
  __shared__ int s[256];
  int t = threadIdx.x;
  s[t] = (t < nb) ? sums[t] : 0;
  __syncthreads();
  if (t == 0) {
    int acc = 0;
    for (int i = 0; i < nb; ++i) { int v = s[i]; s[i] = acc; acc += v; }
  }
  __syncthreads();
  if (t < nb) sums[t] = s[t];
}

__global__ void scan3_kernel(int* __restrict__ off, const int* __restrict__ sums,
                             int n, int total) {
  int i = blockIdx.x * 256 + threadIdx.x;
  if (i < n) off[i] += sums[i >> 10];
  else if (i == n) off[n] = total;
}

__global__ void scatter_kernel(const int* __restrict__ ei, const int* __restrict__ off,
                               int* __restrict__ cnt2, int* __restrict__ ssrc,
                               int E, int E2) {
  int e = blockIdx.x * 256 + threadIdx.x;
  if (e >= E2) return;
  int s, d;
  if (e < E) { s = ei[e]; d = ei[E + e]; } else { s = d = e - E; }
  int p = off[d] + atomicAdd(&cnt2[d], 1);
  ssrc[p] = s;
}

// ---------------- fp32 GEMM: C[M x BN] = A[M x 128] * W[128 x BN] ----------------

template <int BN, int TN>
__global__ __launch_bounds__(256) void gemm_f32(const float* __restrict__ A,
                                                const float* __restrict__ W,
                                                float* __restrict__ C, int M) {
  constexpr int BM = 64, TM = 4, BK = 32;
  constexpr int TX = BN / TN;  // 16
  __shared__ float As[BK][BM];  // transposed A tile
  __shared__ float Ws[BK][BN];
  int tid = threadIdx.x;
  int tx = tid % TX;
  int ty = tid / TX;
  int row0 = blockIdx.x * BM;
  float acc[TM][TN] = {};
  for (int kb = 0; kb < 128; kb += BK) {
    for (int i = tid; i < BM * BK / 4; i += 256) {
      int r = i >> 3;      // BK/4 = 8 float4 per row
      int k4 = i & 7;
      float4 v = make_float4(0.f, 0.f, 0.f, 0.f);
      if (row0 + r < M)
        v = *reinterpret_cast<const float4*>(A + (size_t)(row0 + r) * 128 + kb + k4 * 4);
      As[k4 * 4 + 0][r] = v.x;
      As[k4 * 4 + 1][r] = v.y;
      As[k4 * 4 + 2][r] = v.z;
      As[k4 * 4 + 3][r] = v.w;
    }
    for (int i = tid; i < BK * BN / 4; i += 256) {
      reinterpret_cast<float4*>(&Ws[0][0])[i] =
          *reinterpret_cast<const float4*>(W + (size_t)kb * BN + i * 4);
    }
    __syncthreads();
#pragma unroll
    for (int k = 0; k < BK; ++k) {
      float a[TM], b[TN];
#pragma unroll
      for (int i = 0; i < TM; ++i) a[i] = As[k][ty * TM + i];
#pragma unroll
      for (int j = 0; j < TN; ++j) b[j] = Ws[k][tx * TN + j];
#pragma unroll
      for (int i = 0; i < TM; ++i)
#pragma unroll
        for (int j = 0; j < TN; ++j) acc[i][j] = fmaf(a[i], b[j], acc[i][j]);
    }
    __syncthreads();
  }
#pragma unroll
  for (int i = 0; i < TM; ++i) {
    int r = row0 + ty * TM + i;
    if (r < M) {
#pragma unroll
      for (int j = 0; j < TN; j += 4) {
        float4 v = make_float4(acc[i][j], acc[i][j + 1], acc[i][j + 2], acc[i][j + 3]);
        *reinterpret_cast<float4*>(C + (size_t)r * BN + tx * TN + j) = v;
      }
    }
  }
}

// ---------------- attention scores (per-node dot products) ----------------

__global__ void escore1_kernel(const float* __restrict__ h, const float* __restrict__ a_src,
                               const float* __restrict__ a_dst, float* __restrict__ es,
                               float* __restrict__ ed, int n) {
  int w = (blockIdx.x * 256 + threadIdx.x) >> 6;
  int lane = threadIdx.x & 63;
  if (w >= n) return;
  float v0 = h[(size_t)w * 128 + lane];
  float v1 = h[(size_t)w * 128 + 64 + lane];
  float s0 = v0 * a_src[lane];
  float s1 = v1 * a_src[64 + lane];
  float d0 = v0 * a_dst[lane];
  float d1 = v1 * a_dst[64 + lane];
  for (int o = 32; o; o >>= 1) {
    s0 += __shfl_down(s0, o);
    s1 += __shfl_down(s1, o);
    d0 += __shfl_down(d0, o);
    d1 += __shfl_down(d1, o);
  }
  if (lane == 0) {
    es[w * 2] = s0; es[w * 2 + 1] = s1;
    ed[w * 2] = d0; ed[w * 2 + 1] = d1;
  }
}

__global__ void escore2_kernel(const float* __restrict__ h, const float* __restrict__ a_src,
                               const float* __restrict__ a_dst, float* __restrict__ es,
                               float* __restrict__ ed, int n) {
  int w = (blockIdx.x * 256 + threadIdx.x) >> 6;
  int lane = threadIdx.x & 63;
  if (w >= n) return;
  float v = h[(size_t)w * 64 + lane];
  float s = v * a_src[lane];
  float d = v * a_dst[lane];
  for (int o = 32; o; o >>= 1) {
    s += __shfl_down(s, o);
    d += __shfl_down(d, o);
  }
  if (lane == 0) { es[w] = s; ed[w] = d; }
}

// ---------------- normalized edge-weight prepass (wave per node) ----------------
// Lanes parallel over the node's edges: compute exp(lrelu(es[src]+ed[dst])),
// wave-reduce denominator, store w/den. Removes es-gather + exp + div from agg.

__global__ void wprep1_kernel(const float* __restrict__ es, const float* __restrict__ ed,
                              const int* __restrict__ off, const int* __restrict__ ssrc,
                              float2* __restrict__ wgt, int n) {
  int w = __builtin_amdgcn_readfirstlane((blockIdx.x * 256 + threadIdx.x) >> 6);
  int lane = threadIdx.x & 63;
  if (w >= n) return;
  float ed0 = ed[w * 2], ed1 = ed[w * 2 + 1];
  int e0 = off[w], e1 = off[w + 1];
  const float2* esv = reinterpret_cast<const float2*>(es);
  float den0 = 0.f, den1 = 0.f;
  for (int base = e0; base < e1; base += 64) {
    int e = base + lane;
    float w0 = 0.f, w1 = 0.f;
    if (e < e1) {
      int s = ssrc[e];
      float2 ev = esv[s];
      w0 = __expf(LRELU(ev.x + ed0));
      w1 = __expf(LRELU(ev.y + ed1));
      wgt[e] = make_float2(w0, w1);   // raw; rescaled below
    }
    den0 += w0;
    den1 += w1;
  }
  for (int o = 1; o < 64; o <<= 1) {
    den0 += __shfl_xor(den0, o);
    den1 += __shfl_xor(den1, o);
  }
  float i0 = 1.0f / den0, i1 = 1.0f / den1;
  for (int base = e0; base < e1; base += 64) {
    int e = base + lane;
    if (e < e1) {
      float2 v = wgt[e];               // L1/L2 hit
      wgt[e] = make_float2(v.x * i0, v.y * i1);
    }
  }
}

__global__ void wprep2_kernel(const float* __restrict__ es, const float* __restrict__ ed,
                              const int* __restrict__ off, const int* __restrict__ ssrc,
                              float* __restrict__ wgt, int n) {
  int w = __builtin_amdgcn_readfirstlane((blockIdx.x * 256 + threadIdx.x) >> 6);
  int lane = threadIdx.x & 63;
  if (w >= n) return;
  float edv = ed[w];
  int e0 = off[w], e1 = off[w + 1];
  float den = 0.f;
  for (int base = e0; base < e1; base += 64) {
    int e = base + lane;
    float wv = 0.f;
    if (e < e1) {
      int s = ssrc[e];
      wv = __expf(LRELU(es[s] + edv));
      wgt[e] = wv;
    }
    den += wv;
  }
  for (int o = 1; o < 64; o <<= 1) den += __shfl_xor(den, o);
  float inv = 1.0f / den;
  for (int base = e0; base < e1; base += 64) {
    int e = base + lane;
    if (e < e1) wgt[e] = wgt[e] * inv;
  }
}

// ---------------- aggregation (wave per dst node, atomic-free) ----------------
// agg1: lane l covers channels {2l, 2l+1}; lanes 0-31 = head0, 32-63 = head1.
// One dwordx2 gather per edge, x4 unrolled.

__global__ void agg1_kernel(const float* __restrict__ h, const float2* __restrict__ wgt,
                            const int* __restrict__ off, const int* __restrict__ ssrc,
                            const float* __restrict__ b, float* __restrict__ out, int n) {
  int w = __builtin_amdgcn_readfirstlane((blockIdx.x * 256 + threadIdx.x) >> 6);
  int lane = threadIdx.x & 63;
  if (w >= n) return;
  const float2* hv = reinterpret_cast<const float2*>(h);  // 64 float2 per row
  bool hi = lane >= 32;  // head 1
  float ax = 0.f, ay = 0.f;
  int e0 = off[w], e1 = off[w + 1];
  int e = e0;
  for (; e + 4 <= e1; e += 4) {
    int s0 = ssrc[e], s1 = ssrc[e + 1], s2 = ssrc[e + 2], s3 = ssrc[e + 3];
    float2 w0 = wgt[e], w1 = wgt[e + 1], w2 = wgt[e + 2], w3 = wgt[e + 3];
    float2 g0 = hv[(size_t)s0 * 64 + lane];
    float2 g1 = hv[(size_t)s1 * 64 + lane];
    float2 g2 = hv[(size_t)s2 * 64 + lane];
    float2 g3 = hv[(size_t)s3 * 64 + lane];
    float a0 = hi ? w0.y : w0.x;
    float a1 = hi ? w1.y : w1.x;
    float a2 = hi ? w2.y : w2.x;
    float a3 = hi ? w3.y : w3.x;
    ax = fmaf(a0, g0.x, ax); ay = fmaf(a0, g0.y, ay);
    ax = fmaf(a1, g1.x, ax); ay = fmaf(a1, g1.y, ay);
    ax = fmaf(a2, g2.x, ax); ay = fmaf(a2, g2.y, ay);
    ax = fmaf(a3, g3.x, ax); ay = fmaf(a3, g3.y, ay);
  }
  for (; e < e1; ++e) {
    int s = ssrc[e];
    float2 wv = wgt[e];
    float2 g = hv[(size_t)s * 64 + lane];
    float a = hi ? wv.y : wv.x;
    ax = fmaf(a, g.x, ax); ay = fmaf(a, g.y, ay);
  }
  float2 bb = reinterpret_cast<const float2*>(b)[lane];
  float2 o2 = make_float2(fmaxf(ax + bb.x, 0.f), fmaxf(ay + bb.y, 0.f));  // ReLU
  reinterpret_cast<float2*>(out)[(size_t)w * 64 + lane] = o2;
}

__global__ void agg2_kernel(const float* __restrict__ h, const float* __restrict__ wgt,
                            const int* __restrict__ off, const int* __restrict__ ssrc,
                            const float* __restrict__ b, float* __restrict__ out, int n) {
  int w = __builtin_amdgcn_readfirstlane((blockIdx.x * 256 + threadIdx.x) >> 6);
  int lane = threadIdx.x & 63;
  if (w >= n) return;
  float acc = 0.f;
  int e0 = off[w], e1 = off[w + 1];
  int e = e0;
  for (; e + 4 <= e1; e += 4) {
    int s0 = ssrc[e], s1 = ssrc[e + 1], s2 = ssrc[e + 2], s3 = ssrc[e + 3];
    float w0 = wgt[e], w1 = wgt[e + 1], w2 = wgt[e + 2], w3 = wgt[e + 3];
    float g0 = h[(size_t)s0 * 64 + lane];
    float g1 = h[(size_t)s1 * 64 + lane];
    float g2 = h[(size_t)s2 * 64 + lane];
    float g3 = h[(size_t)s3 * 64 + lane];
    acc = fmaf(w0, g0, acc);
    acc = fmaf(w1, g1, acc);
    acc = fmaf(w2, g2, acc);
    acc = fmaf(w3, g3, acc);
  }
  for (; e < e1; ++e) {
    acc = fmaf(wgt[e], h[(size_t)ssrc[e] * 64 + lane], acc);
  }
  out[(size_t)w * 64 + lane] = acc + b[lane];    // no ReLU after layer 2
}

// ---------------- pooling + MLP ----------------

__global__ void pool_kernel(const float* __restrict__ x, const int* __restrict__ batch,
                            float* __restrict__ pooled, float* __restrict__ cnt, int n) {
  int w = (blockIdx.x * 256 + threadIdx.x) >> 6;
  int lane = threadIdx.x & 63;
  int n0 = w * 64;
  if (n0 >= n) return;
  int n1 = min(n, n0 + 64);
  float acc = 0.f;
  int cur = batch[n0];
  int run = 0;
  for (int i = n0; i < n1; ++i) {
    int g = batch[i];
    if (g != cur) {
      atomicAdd(&pooled[cur * 64 + lane], acc);
      if (lane == 0) atomicAdd(&cnt[cur], (float)run);
      acc = 0.f; run = 0; cur = g;
    }
    acc += x[(size_t)i * 64 + lane];
    ++run;
  }
  atomicAdd(&pooled[cur * 64 + lane], acc);
  if (lane == 0) atomicAdd(&cnt[cur], (float)run);
}

__global__ void mlp1_kernel(const float* __restrict__ pooled, const float* __restrict__ cnt,
                            const float* __restrict__ dw1, const float* __restrict__ db1,
                            float* __restrict__ z) {
  int g = blockIdx.x;
  int c = threadIdx.x;  // 64
  __shared__ float P[64];
  float inv = 1.0f / fmaxf(cnt[g], 1.0f);
  P[c] = pooled[g * 64 + c] * inv;
  __syncthreads();
  float s = db1[c];
#pragma unroll
  for (int k = 0; k < 64; ++k) s = fmaf(P[k], dw1[k * 64 + c], s);
  z[g * 64 + c] = fmaxf(s, 0.f);
}

__global__ void mlp2_kernel(const float* __restrict__ z, const float* __restrict__ dw2,
                            const float* __restrict__ db2, float* __restrict__ out) {
  int g = blockIdx.x;
  int o = threadIdx.x;  // 16
  __shared__ float Z[64];
  for (int i = o; i < 64; i += 16) Z[i] = z[g * 64 + i];
  __syncthreads();
  float s = db2[o];
#pragma unroll
  for (int c = 0; c < 64; ++c) s = fmaf(Z[c], dw2[c * 16 + o], s);
  out[g * 16 + o] = s;
}

// ---------------- launch ----------------

extern "C" void kernel_launch(void* const* d_in, const int* in_sizes, int n_in,
                              void* d_out, int out_size, void* d_ws, size_t ws_size,
                              hipStream_t stream) {
  const float* x      = (const float*)d_in[0];
  const int*   ei     = (const int*)d_in[1];
  const int*   batch  = (const int*)d_in[2];
  const float* W1     = (const float*)d_in[3];
  const float* a_src1 = (const float*)d_in[4];
  const float* a_dst1 = (const float*)d_in[5];
  const float* b1     = (const float*)d_in[6];
  const float* W2     = (const float*)d_in[7];
  const float* a_src2 = (const float*)d_in[8];
  const float* a_dst2 = (const float*)d_in[9];
  const float* b2     = (const float*)d_in[10];
  const float* dw1    = (const float*)d_in[11];
  const float* db1    = (const float*)d_in[12];
  const float* dw2    = (const float*)d_in[13];
  const float* db2    = (const float*)d_in[14];
  float* out = (float*)d_out;

  const int N = in_sizes[2];
  const int E = in_sizes[1] / 2;
  const int E2 = E + N;
  const int G = out_size / 16;

  char* ws = (char*)d_ws;
  size_t o = 0;
  auto alloc = [&](size_t bytes) {
    void* p = ws + o;
    o = (o + bytes + 255) & ~(size_t)255;
    return p;
  };
  int*    deg    = (int*)alloc((size_t)N * 4);
  int*    cnt2   = (int*)alloc((size_t)N * 4);
  int*    off    = (int*)alloc((size_t)(N + 1) * 4);
  int*    sums   = (int*)alloc(1024);
  int*    ssrc   = (int*)alloc((size_t)E2 * 4);
  float*  es1    = (float*)alloc((size_t)N * 2 * 4);
  float*  ed1    = (float*)alloc((size_t)N * 2 * 4);
  float*  es2    = (float*)alloc((size_t)N * 4);
  float*  ed2    = (float*)alloc((size_t)N * 4);
  float2* wgt1   = (float2*)alloc((size_t)E2 * 8);
  float*  wgt2   = (float*)alloc((size_t)E2 * 4);
  float*  pooled = (float*)alloc((size_t)G * 64 * 4);
  float*  cntf   = (float*)alloc((size_t)G * 4);
  float*  zbuf   = (float*)alloc((size_t)G * 64 * 4);
  float*  bufA   = (float*)alloc((size_t)N * 128 * 4);  // h1, then h2
  float*  bufB   = (float*)alloc((size_t)N * 128 * 4);  // out1, then out2

  hipMemsetAsync(deg, 0, (size_t)N * 4, stream);
  hipMemsetAsync(cnt2, 0, (size_t)N * 4, stream);
  hipMemsetAsync(pooled, 0, (size_t)G * 64 * 4, stream);
  hipMemsetAsync(cntf, 0, (size_t)G * 4, stream);

  int gE2 = (E2 + 255) / 256;
  hist_kernel<<<gE2, 256, 0, stream>>>(ei, deg, E, E2);
  int nb = (N + 1023) / 1024;
  scan1_kernel<<<nb, 256, 0, stream>>>(deg, off, sums, N);
  scan2_kernel<<<1, 256, 0, stream>>>(sums, nb);
  scan3_kernel<<<(N + 256) / 256, 256, 0, stream>>>(off, sums, N, E2);
  scatter_kernel<<<gE2, 256, 0, stream>>>(ei, off, cnt2, ssrc, E, E2);

  int gM = (N + 63) / 64;
  int gW = (N + 3) / 4;  // wave-per-node kernels, 4 waves/block

  // layer 1
  gemm_f32<128, 8><<<gM, 256, 0, stream>>>(x, W1, bufA, N);
  escore1_kernel<<<gW, 256, 0, stream>>>(bufA, a_src1, a_dst1, es1, ed1, N);
  wprep1_kernel<<<gW, 256, 0, stream>>>(es1, ed1, off, ssrc, wgt1, N);
  agg1_kernel<<<gW, 256, 0, stream>>>(bufA, wgt1, off, ssrc, b1, bufB, N);

  // layer 2
  gemm_f32<64, 4><<<gM, 256, 0, stream>>>(bufB, W2, bufA, N);
  escore2_kernel<<<gW, 256, 0, stream>>>(bufA, a_src2, a_dst2, es2, ed2, N);
  wprep2_kernel<<<gW, 256, 0, stream>>>(es2, ed2, off, ssrc, wgt2, N);
  agg2_kernel<<<gW, 256, 0, stream>>>(bufA, wgt2, off, ssrc, b2, bufB, N);

  // pool + MLP
  int nwPool = (N + 63) / 64;
  pool_kernel<<<(nwPool + 3) / 4, 256, 0, stream>>>(bufB, batch, pooled, cntf, N);
  mlp1_kernel<<<G, 64, 0, stream>>>(pooled, cntf, dw1, db1, zbuf);
  mlp2_kernel<<<G, 16, 0, stream>>>(zbuf, dw2, db2, out);
}

// Round 3
// 596.227 us; speedup vs baseline: 1.3215x; 1.1088x over previous
//
#include <hip/hip_runtime.h>
#include <stdint.h>

// ---------------------------------------------------------------------------
// SpatialGNN: 2x GATConv (2 heads -> 1 head), mean-pool per graph, MLP.
// CSR build once per launch -> atomic-free aggregation.
// R3: h1/h2 stored as bf16 (converted in GEMM epilogue) -> agg gathers halve
//     in bytes; agg unroll x8. Accumulation stays fp32.
// ---------------------------------------------------------------------------

#define LRELU(x) ((x) > 0.f ? (x) : 0.2f * (x))

__device__ __forceinline__ uint16_t f2bf(float f) {
  uint32_t u = __float_as_uint(f);
  u += 0x7fff + ((u >> 16) & 1);   // RNE
  return (uint16_t)(u >> 16);
}
__device__ __forceinline__ float bf2f(uint16_t b) {
  return __uint_as_float(((uint32_t)b) << 16);
}

// ---------------- CSR build ----------------

__global__ void hist_kernel(const int* __restrict__ ei, int* __restrict__ deg,
                            int E, int E2) {
  int e = blockIdx.x * 256 + threadIdx.x;
  if (e >= E2) return;
  int d = (e < E) ? ei[E + e] : (e - E);   // self-loop for e >= E
  atomicAdd(&deg[d], 1);
}

__global__ void scan1_kernel(const int* __restrict__ deg, int* __restrict__ off,
                             int* __restrict__ sums, int n) {
  __shared__ int s[256];
  int t = threadIdx.x;
  int base = blockIdx.x * 1024 + t * 4;
  int v0 = (base + 0 < n) ? deg[base + 0] : 0;
  int v1 = (base + 1 < n) ? deg[base + 1] : 0;
  int v2 = (base + 2 < n) ? deg[base + 2] : 0;
  int v3 = (base + 3 < n) ? deg[base + 3] : 0;
  int sum = v0 + v1 + v2 + v3;
  s[t] = sum;
  __syncthreads();
  for (int d = 1; d < 256; d <<= 1) {
    int x = (t >= d) ? s[t - d] : 0;
    __syncthreads();
    s[t] += x;
    __syncthreads();
  }
  if (t == 255) sums[blockIdx.x] = s[255];
  int run = s[t] - sum;  // exclusive prefix within chunk
  if (base + 0 < n) { off[base + 0] = run; run += v0; }
  if (base + 1 < n) { off[base + 1] = run; run += v1; }
  if (base + 2 < n) { off[base + 2] = run; run += v2; }
  if (base + 3 < n) { off[base + 3] = run; }
}

__global__ void scan2_kernel(int* __restrict__ sums, int nb) {
  __shared__ int s[256];
  int t = threadIdx.x;
  s[t] = (t < nb) ? sums[t] : 0;
  __syncthreads();
  if (t == 0) {
    int acc = 0;
    for (int i = 0; i < nb; ++i) { int v = s[i]; s[i] = acc; acc += v; }
  }
  __syncthreads();
  if (t < nb) sums[t] = s[t];
}

__global__ void scan3_kernel(int* __restrict__ off, const int* __restrict__ sums,
                             int n, int total) {
  int i = blockIdx.x * 256 + threadIdx.x;
  if (i < n) off[i] += sums[i >> 10];
  else if (i == n) off[n] = total;
}

__global__ void scatter_kernel(const int* __restrict__ ei, const int* __restrict__ off,
                               int* __restrict__ cnt2, int* __restrict__ ssrc,
                               int E, int E2) {
  int e = blockIdx.x * 256 + threadIdx.x;
  if (e >= E2) return;
  int s, d;
  if (e < E) { s = ei[e]; d = ei[E + e]; } else { s = d = e - E; }
  int p = off[d] + atomicAdd(&cnt2[d], 1);
  ssrc[p] = s;
}

// ---------------- fp32 GEMM: Cb[M x BN](bf16) = A[M x 128] * W[128 x BN] ------

template <int BN, int TN>
__global__ __launch_bounds__(256) void gemm_f32_bf16out(const float* __restrict__ A,
                                                        const float* __restrict__ W,
                                                        uint16_t* __restrict__ Cb, int M) {
  constexpr int BM = 64, TM = 4, BK = 32;
  constexpr int TX = BN / TN;  // 16
  __shared__ float As[BK][BM];  // transposed A tile
  __shared__ float Ws[BK][BN];
  int tid = threadIdx.x;
  int tx = tid % TX;
  int ty = tid / TX;
  int row0 = blockIdx.x * BM;
  float acc[TM][TN] = {};
  for (int kb = 0; kb < 128; kb += BK) {
    for (int i = tid; i < BM * BK / 4; i += 256) {
      int r = i >> 3;      // BK/4 = 8 float4 per row
      int k4 = i & 7;
      float4 v = make_float4(0.f, 0.f, 0.f, 0.f);
      if (row0 + r < M)
        v = *reinterpret_cast<const float4*>(A + (size_t)(row0 + r) * 128 + kb + k4 * 4);
      As[k4 * 4 + 0][r] = v.x;
      As[k4 * 4 + 1][r] = v.y;
      As[k4 * 4 + 2][r] = v.z;
      As[k4 * 4 + 3][r] = v.w;
    }
    for (int i = tid; i < BK * BN / 4; i += 256) {
      reinterpret_cast<float4*>(&Ws[0][0])[i] =
          *reinterpret_cast<const float4*>(W + (size_t)kb * BN + i * 4);
    }
    __syncthreads();
#pragma unroll
    for (int k = 0; k < BK; ++k) {
      float a[TM], b[TN];
#pragma unroll
      for (int i = 0; i < TM; ++i) a[i] = As[k][ty * TM + i];
#pragma unroll
      for (int j = 0; j < TN; ++j) b[j] = Ws[k][tx * TN + j];
#pragma unroll
      for (int i = 0; i < TM; ++i)
#pragma unroll
        for (int j = 0; j < TN; ++j) acc[i][j] = fmaf(a[i], b[j], acc[i][j]);
    }
    __syncthreads();
  }
#pragma unroll
  for (int i = 0; i < TM; ++i) {
    int r = row0 + ty * TM + i;
    if (r < M) {
      uint32_t pk[TN / 2];
#pragma unroll
      for (int j = 0; j < TN; j += 2)
        pk[j / 2] = (uint32_t)f2bf(acc[i][j]) | ((uint32_t)f2bf(acc[i][j + 1]) << 16);
      uint32_t* dst = reinterpret_cast<uint32_t*>(Cb + (size_t)r * BN + tx * TN);
#pragma unroll
      for (int j = 0; j < TN / 2; ++j) dst[j] = pk[j];
    }
  }
}

// ---------------- attention scores (per-node dot products, bf16 h) ------------

__global__ void escore1_kernel(const uint16_t* __restrict__ h, const float* __restrict__ a_src,
                               const float* __restrict__ a_dst, float* __restrict__ es,
                               float* __restrict__ ed, int n) {
  int w = (blockIdx.x * 256 + threadIdx.x) >> 6;
  int lane = threadIdx.x & 63;
  if (w >= n) return;
  float v0 = bf2f(h[(size_t)w * 128 + lane]);
  float v1 = bf2f(h[(size_t)w * 128 + 64 + lane]);
  float s0 = v0 * a_src[lane];
  float s1 = v1 * a_src[64 + lane];
  float d0 = v0 * a_dst[lane];
  float d1 = v1 * a_dst[64 + lane];
  for (int o = 32; o; o >>= 1) {
    s0 += __shfl_down(s0, o);
    s1 += __shfl_down(s1, o);
    d0 += __shfl_down(d0, o);
    d1 += __shfl_down(d1, o);
  }
  if (lane == 0) {
    es[w * 2] = s0; es[w * 2 + 1] = s1;
    ed[w * 2] = d0; ed[w * 2 + 1] = d1;
  }
}

__global__ void escore2_kernel(const uint16_t* __restrict__ h, const float* __restrict__ a_src,
                               const float* __restrict__ a_dst, float* __restrict__ es,
                               float* __restrict__ ed, int n) {
  int w = (blockIdx.x * 256 + threadIdx.x) >> 6;
  int lane = threadIdx.x & 63;
  if (w >= n) return;
  float v = bf2f(h[(size_t)w * 64 + lane]);
  float s = v * a_src[lane];
  float d = v * a_dst[lane];
  for (int o = 32; o; o >>= 1) {
    s += __shfl_down(s, o);
    d += __shfl_down(d, o);
  }
  if (lane == 0) { es[w] = s; ed[w] = d; }
}

// ---------------- normalized edge-weight prepass (wave per node) --------------

__global__ void wprep1_kernel(const float* __restrict__ es, const float* __restrict__ ed,
                              const int* __restrict__ off, const int* __restrict__ ssrc,
                              float2* __restrict__ wgt, int n) {
  int w = __builtin_amdgcn_readfirstlane((blockIdx.x * 256 + threadIdx.x) >> 6);
  int lane = threadIdx.x & 63;
  if (w >= n) return;
  float ed0 = ed[w * 2], ed1 = ed[w * 2 + 1];
  int e0 = off[w], e1 = off[w + 1];
  const float2* esv = reinterpret_cast<const float2*>(es);
  float den0 = 0.f, den1 = 0.f;
  for (int base = e0; base < e1; base += 64) {
    int e = base + lane;
    float w0 = 0.f, w1 = 0.f;
    if (e < e1) {
      int s = ssrc[e];
      float2 ev = esv[s];
      w0 = __expf(LRELU(ev.x + ed0));
      w1 = __expf(LRELU(ev.y + ed1));
      wgt[e] = make_float2(w0, w1);   // raw; rescaled below
    }
    den0 += w0;
    den1 += w1;
  }
  for (int o = 1; o < 64; o <<= 1) {
    den0 += __shfl_xor(den0, o);
    den1 += __shfl_xor(den1, o);
  }
  float i0 = 1.0f / den0, i1 = 1.0f / den1;
  for (int base = e0; base < e1; base += 64) {
    int e = base + lane;
    if (e < e1) {
      float2 v = wgt[e];               // L1/L2 hit
      wgt[e] = make_float2(v.x * i0, v.y * i1);
    }
  }
}

__global__ void wprep2_kernel(const float* __restrict__ es, const float* __restrict__ ed,
                              const int* __restrict__ off, const int* __restrict__ ssrc,
                              float* __restrict__ wgt, int n) {
  int w = __builtin_amdgcn_readfirstlane((blockIdx.x * 256 + threadIdx.x) >> 6);
  int lane = threadIdx.x & 63;
  if (w >= n) return;
  float edv = ed[w];
  int e0 = off[w], e1 = off[w + 1];
  float den = 0.f;
  for (int base = e0; base < e1; base += 64) {
    int e = base + lane;
    float wv = 0.f;
    if (e < e1) {
      int s = ssrc[e];
      wv = __expf(LRELU(es[s] + edv));
      wgt[e] = wv;
    }
    den += wv;
  }
  for (int o = 1; o < 64; o <<= 1) den += __shfl_xor(den, o);
  float inv = 1.0f / den;
  for (int base = e0; base < e1; base += 64) {
    int e = base + lane;
    if (e < e1) wgt[e] = wgt[e] * inv;
  }
}

// ---------------- aggregation (wave per dst node, atomic-free, bf16 gathers) --
// agg1: lane l covers channels {2l, 2l+1} via one 4B ushort2 load per edge.

__global__ void agg1_kernel(const uint32_t* __restrict__ hv, const float2* __restrict__ wgt,
                            const int* __restrict__ off, const int* __restrict__ ssrc,
                            const float* __restrict__ b, float* __restrict__ out, int n) {
  int w = __builtin_amdgcn_readfirstlane((blockIdx.x * 256 + threadIdx.x) >> 6);
  int lane = threadIdx.x & 63;
  if (w >= n) return;
  bool hi = lane >= 32;  // head 1
  float ax = 0.f, ay = 0.f;
  int e0 = off[w], e1 = off[w + 1];
  int e = e0;
  for (; e + 8 <= e1; e += 8) {
    int s[8];
    float2 wv[8];
    uint32_t g[8];
#pragma unroll
    for (int u = 0; u < 8; ++u) { s[u] = ssrc[e + u]; wv[u] = wgt[e + u]; }
#pragma unroll
    for (int u = 0; u < 8; ++u) g[u] = hv[(size_t)s[u] * 64 + lane];
#pragma unroll
    for (int u = 0; u < 8; ++u) {
      float a = hi ? wv[u].y : wv[u].x;
      ax = fmaf(a, __uint_as_float(g[u] << 16), ax);
      ay = fmaf(a, __uint_as_float(g[u] & 0xffff0000u), ay);
    }
  }
  for (; e + 4 <= e1; e += 4) {
    int s[4];
    float2 wv[4];
    uint32_t g[4];
#pragma unroll
    for (int u = 0; u < 4; ++u) { s[u] = ssrc[e + u]; wv[u] = wgt[e + u]; }
#pragma unroll
    for (int u = 0; u < 4; ++u) g[u] = hv[(size_t)s[u] * 64 + lane];
#pragma unroll
    for (int u = 0; u < 4; ++u) {
      float a = hi ? wv[u].y : wv[u].x;
      ax = fmaf(a, __uint_as_float(g[u] << 16), ax);
      ay = fmaf(a, __uint_as_float(g[u] & 0xffff0000u), ay);
    }
  }
  for (; e < e1; ++e) {
    int s = ssrc[e];
    float2 wv = wgt[e];
    uint32_t g = hv[(size_t)s * 64 + lane];
    float a = hi ? wv.y : wv.x;
    ax = fmaf(a, __uint_as_float(g << 16), ax);
    ay = fmaf(a, __uint_as_float(g & 0xffff0000u), ay);
  }
  float2 bb = reinterpret_cast<const float2*>(b)[lane];
  float2 o2 = make_float2(fmaxf(ax + bb.x, 0.f), fmaxf(ay + bb.y, 0.f));  // ReLU
  reinterpret_cast<float2*>(out)[(size_t)w * 64 + lane] = o2;
}

__global__ void agg2_kernel(const uint16_t* __restrict__ h, const float* __restrict__ wgt,
                            const int* __restrict__ off, const int* __restrict__ ssrc,
                            const float* __restrict__ b, float* __restrict__ out, int n) {
  int w = __builtin_amdgcn_readfirstlane((blockIdx.x * 256 + threadIdx.x) >> 6);
  int lane = threadIdx.x & 63;
  if (w >= n) return;
  float acc = 0.f;
  int e0 = off[w], e1 = off[w + 1];
  int e = e0;
  for (; e + 8 <= e1; e += 8) {
    int s[8];
    float wv[8];
    uint16_t g[8];
#pragma unroll
    for (int u = 0; u < 8; ++u) { s[u] = ssrc[e + u]; wv[u] = wgt[e + u]; }
#pragma unroll
    for (int u = 0; u < 8; ++u) g[u] = h[(size_t)s[u] * 64 + lane];
#pragma unroll
    for (int u = 0; u < 8; ++u) acc = fmaf(wv[u], bf2f(g[u]), acc);
  }
  for (; e + 4 <= e1; e += 4) {
    int s[4];
    float wv[4];
    uint16_t g[4];
#pragma unroll
    for (int u = 0; u < 4; ++u) { s[u] = ssrc[e + u]; wv[u] = wgt[e + u]; }
#pragma unroll
    for (int u = 0; u < 4; ++u) g[u] = h[(size_t)s[u] * 64 + lane];
#pragma unroll
    for (int u = 0; u < 4; ++u) acc = fmaf(wv[u], bf2f(g[u]), acc);
  }
  for (; e < e1; ++e) {
    acc = fmaf(wgt[e], bf2f(h[(size_t)ssrc[e] * 64 + lane]), acc);
  }
  out[(size_t)w * 64 + lane] = acc + b[lane];    // no ReLU after layer 2
}

// ---------------- pooling + MLP ----------------

__global__ void pool_kernel(const float* __restrict__ x, const int* __restrict__ batch,
                            float* __restrict__ pooled, float* __restrict__ cnt, int n) {
  int w = (blockIdx.x * 256 + threadIdx.x) >> 6;
  int lane = threadIdx.x & 63;
  int n0 = w * 64;
  if (n0 >= n) return;
  int n1 = min(n, n0 + 64);
  float acc = 0.f;
  int cur = batch[n0];
  int run = 0;
  for (int i = n0; i < n1; ++i) {
    int g = batch[i];
    if (g != cur) {
      atomicAdd(&pooled[cur * 64 + lane], acc);
      if (lane == 0) atomicAdd(&cnt[cur], (float)run);
      acc = 0.f; run = 0; cur = g;
    }
    acc += x[(size_t)i * 64 + lane];
    ++run;
  }
  atomicAdd(&pooled[cur * 64 + lane], acc);
  if (lane == 0) atomicAdd(&cnt[cur], (float)run);
}

__global__ void mlp1_kernel(const float* __restrict__ pooled, const float* __restrict__ cnt,
                            const float* __restrict__ dw1, const float* __restrict__ db1,
                            float* __restrict__ z) {
  int g = blockIdx.x;
  int c = threadIdx.x;  // 64
  __shared__ float P[64];
  float inv = 1.0f / fmaxf(cnt[g], 1.0f);
  P[c] = pooled[g * 64 + c] * inv;
  __syncthreads();
  float s = db1[c];
#pragma unroll
  for (int k = 0; k < 64; ++k) s = fmaf(P[k], dw1[k * 64 + c], s);
  z[g * 64 + c] = fmaxf(s, 0.f);
}

__global__ void mlp2_kernel(const float* __restrict__ z, const float* __restrict__ dw2,
                            const float* __restrict__ db2, float* __restrict__ out) {
  int g = blockIdx.x;
  int o = threadIdx.x;  // 16
  __shared__ float Z[64];
  for (int i = o; i < 64; i += 16) Z[i] = z[g * 64 + i];
  __syncthreads();
  float s = db2[o];
#pragma unroll
  for (int c = 0; c < 64; ++c) s = fmaf(Z[c], dw2[c * 16 + o], s);
  out[g * 16 + o] = s;
}

// ---------------- launch ----------------

extern "C" void kernel_launch(void* const* d_in, const int* in_sizes, int n_in,
                              void* d_out, int out_size, void* d_ws, size_t ws_size,
                              hipStream_t stream) {
  const float* x      = (const float*)d_in[0];
  const int*   ei     = (const int*)d_in[1];
  const int*   batch  = (const int*)d_in[2];
  const float* W1     = (const float*)d_in[3];
  const float* a_src1 = (const float*)d_in[4];
  const float* a_dst1 = (const float*)d_in[5];
  const float* b1     = (const float*)d_in[6];
  const float* W2     = (const float*)d_in[7];
  const float* a_src2 = (const float*)d_in[8];
  const float* a_dst2 = (const float*)d_in[9];
  const float* b2     = (const float*)d_in[10];
  const float* dw1    = (const float*)d_in[11];
  const float* db1    = (const float*)d_in[12];
  const float* dw2    = (const float*)d_in[13];
  const float* db2    = (const float*)d_in[14];
  float* out = (float*)d_out;

  const int N = in_sizes[2];
  const int E = in_sizes[1] / 2;
  const int E2 = E + N;
  const int G = out_size / 16;

  char* ws = (char*)d_ws;
  size_t o = 0;
  auto alloc = [&](size_t bytes) {
    void* p = ws + o;
    o = (o + bytes + 255) & ~(size_t)255;
    return p;
  };
  int*      degcnt = (int*)alloc((size_t)2 * N * 4);   // deg | cnt2 contiguous
  int*      deg    = degcnt;
  int*      cnt2   = degcnt + N;
  int*      off    = (int*)alloc((size_t)(N + 1) * 4);
  int*      sums   = (int*)alloc(1024);
  int*      ssrc   = (int*)alloc((size_t)E2 * 4);
  float*    es1    = (float*)alloc((size_t)N * 2 * 4);
  float*    ed1    = (float*)alloc((size_t)N * 2 * 4);
  float*    es2    = (float*)alloc((size_t)N * 4);
  float*    ed2    = (float*)alloc((size_t)N * 4);
  float2*   wgt1   = (float2*)alloc((size_t)E2 * 8);
  float*    wgt2   = (float*)alloc((size_t)E2 * 4);
  float*    pooled = (float*)alloc((size_t)G * 64 * 4);
  float*    cntf   = (float*)alloc((size_t)G * 4);
  float*    zbuf   = (float*)alloc((size_t)G * 64 * 4);
  uint16_t* hb1    = (uint16_t*)alloc((size_t)N * 128 * 2);  // bf16 h1
  uint16_t* hb2    = (uint16_t*)alloc((size_t)N * 64 * 2);   // bf16 h2
  float*    out1   = (float*)alloc((size_t)N * 128 * 4);
  float*    out2   = (float*)alloc((size_t)N * 64 * 4);

  hipMemsetAsync(degcnt, 0, (size_t)2 * N * 4, stream);
  hipMemsetAsync(pooled, 0, (size_t)G * 64 * 4, stream);
  hipMemsetAsync(cntf, 0, (size_t)G * 4, stream);

  int gE2 = (E2 + 255) / 256;
  hist_kernel<<<gE2, 256, 0, stream>>>(ei, deg, E, E2);
  int nb = (N + 1023) / 1024;
  scan1_kernel<<<nb, 256, 0, stream>>>(deg, off, sums, N);
  scan2_kernel<<<1, 256, 0, stream>>>(sums, nb);
  scan3_kernel<<<(N + 256) / 256, 256, 0, stream>>>(off, sums, N, E2);
  scatter_kernel<<<gE2, 256, 0, stream>>>(ei, off, cnt2, ssrc, E, E2);

  int gM = (N + 63) / 64;
  int gW = (N + 3) / 4;  // wave-per-node kernels, 4 waves/block

  // layer 1
  gemm_f32_bf16out<128, 8><<<gM, 256, 0, stream>>>(x, W1, hb1, N);
  escore1_kernel<<<gW, 256, 0, stream>>>(hb1, a_src1, a_dst1, es1, ed1, N);
  wprep1_kernel<<<gW, 256, 0, stream>>>(es1, ed1, off, ssrc, wgt1, N);
  agg1_kernel<<<gW, 256, 0, stream>>>((const uint32_t*)hb1, wgt1, off, ssrc, b1, out1, N);

  // layer 2
  gemm_f32_bf16out<64, 4><<<gM, 256, 0, stream>>>(out1, W2, hb2, N);
  escore2_kernel<<<gW, 256, 0, stream>>>(hb2, a_src2, a_dst2, es2, ed2, N);
  wprep2_kernel<<<gW, 256, 0, stream>>>(es2, ed2, off, ssrc, wgt2, N);
  agg2_kernel<<<gW, 256, 0, stream>>>(hb2, wgt2, off, ssrc, b2, out2, N);

  // pool + MLP
  int nwPool = (N + 63) / 64;
  pool_kernel<<<(nwPool + 3) / 4, 256, 0, stream>>>(out2, batch, pooled, cntf, N);
  mlp1_kernel<<<G, 64, 0, stream>>>(pooled, cntf, dw1, db1, zbuf);
  mlp2_kernel<<<G, 16, 0, stream>>>(zbuf, dw2, db2, out);
}

// Round 4
// 565.844 us; speedup vs baseline: 1.3925x; 1.0537x over previous
//
#include <hip/hip_runtime.h>
#include <stdint.h>

// ---------------------------------------------------------------------------
// SpatialGNN: 2x GATConv (2 heads -> 1 head), mean-pool per graph, MLP.
// R4: two-phase (radix-bucket) CSR build to kill random-write line thrash;
//     layer-1 edge weights fused into the final scatter; softmax denominator
//     accumulated in-register inside agg (raw weights stored, no rescale).
//     h1/h2 remain bf16; fp32 accumulation everywhere.
// ---------------------------------------------------------------------------

#define LRELU(x) ((x) > 0.f ? (x) : 0.2f * (x))

__device__ __forceinline__ uint16_t f2bf(float f) {
  uint32_t u = __float_as_uint(f);
  u += 0x7fff + ((u >> 16) & 1);   // RNE
  return (uint16_t)(u >> 16);
}
__device__ __forceinline__ float bf2f(uint16_t b) {
  return __uint_as_float(((uint32_t)b) << 16);
}

// ---------------- CSR build, phase A: bucket by dst>>shift ----------------

__global__ void bcount_kernel(const int* __restrict__ ei, int* __restrict__ bcnt,
                              int E, int E2, int shift, int nb) {
  __shared__ int lh[128];
  int t = threadIdx.x;
  if (t < 128) lh[t] = 0;
  __syncthreads();
  for (int e = blockIdx.x * 256 + t; e < E2; e += gridDim.x * 256) {
    int d = (e < E) ? ei[E + e] : (e - E);
    atomicAdd(&lh[d >> shift], 1);
  }
  __syncthreads();
  if (t < nb) { int v = lh[t]; if (v) atomicAdd(&bcnt[t], v); }
}

__global__ void bscan_kernel(const int* __restrict__ bcnt, int* __restrict__ boff,
                             int* __restrict__ bcur, int nb) {
  if (threadIdx.x == 0) {
    int acc = 0;
    for (int i = 0; i < nb; ++i) { boff[i] = acc; bcur[i] = acc; acc += bcnt[i]; }
    boff[nb] = acc;
  }
}

// Each block bins 2048 edges into bucket-grouped (src,dst) pair runs.
__global__ void bscatter_kernel(const int* __restrict__ ei, int* __restrict__ bcur,
                                int2* __restrict__ bpairs, int E, int E2, int shift) {
  __shared__ int lh[128];
  __shared__ int lb[128];
  int t = threadIdx.x;
  if (t < 128) lh[t] = 0;
  __syncthreads();
  int base = blockIdx.x * 2048;
  int src[8], dst[8], rk[8], bk[8];
#pragma unroll
  for (int u = 0; u < 8; ++u) {
    int e = base + u * 256 + t;
    if (e < E2) {
      int s, d;
      if (e < E) { s = ei[e]; d = ei[E + e]; } else { s = d = e - E; }
      src[u] = s; dst[u] = d; bk[u] = d >> shift;
      rk[u] = atomicAdd(&lh[bk[u]], 1);
    } else rk[u] = -1;
  }
  __syncthreads();
  if (t < 128) { int c = lh[t]; lb[t] = c ? atomicAdd(&bcur[t], c) : 0; }
  __syncthreads();
#pragma unroll
  for (int u = 0; u < 8; ++u) {
    if (rk[u] >= 0) bpairs[lb[bk[u]] + rk[u]] = make_int2(src[u], dst[u]);
  }
}

// Degree histogram over the bucketed pairs (atomics stay in a 4KB window).
__global__ void deghist_kernel(const int2* __restrict__ bpairs, int* __restrict__ deg,
                               int E2) {
  int e = blockIdx.x * 256 + threadIdx.x;
  if (e < E2) atomicAdd(&deg[bpairs[e].y], 1);
}

// ---------------- node-level prefix scan (off = exclusive scan of deg) -------

__global__ void scan1_kernel(const int* __restrict__ deg, int* __restrict__ off,
                             int* __restrict__ sums, int n) {
  __shared__ int s[256];
  int t = threadIdx.x;
  int base = blockIdx.x * 1024 + t * 4;
  int v0 = (base + 0 < n) ? deg[base + 0] : 0;
  int v1 = (base + 1 < n) ? deg[base + 1] : 0;
  int v2 = (base + 2 < n) ? deg[base + 2] : 0;
  int v3 = (base + 3 < n) ? deg[base + 3] : 0;
  int sum = v0 + v1 + v2 + v3;
  s[t] = sum;
  __syncthreads();
  for (int d = 1; d < 256; d <<= 1) {
    int x = (t >= d) ? s[t - d] : 0;
    __syncthreads();
    s[t] += x;
    __syncthreads();
  }
  if (t == 255) sums[blockIdx.x] = s[255];
  int run = s[t] - sum;
  if (base + 0 < n) { off[base + 0] = run; run += v0; }
  if (base + 1 < n) { off[base + 1] = run; run += v1; }
  if (base + 2 < n) { off[base + 2] = run; run += v2; }
  if (base + 3 < n) { off[base + 3] = run; }
}

__global__ void scan2_kernel(int* __restrict__ sums, int nb) {
  __shared__ int s[256];
  int t = threadIdx.x;
  s[t] = (t < nb) ? sums[t] : 0;
  __syncthreads();
  if (t == 0) {
    int acc = 0;
    for (int i = 0; i < nb; ++i) { int v = s[i]; s[i] = acc; acc += v; }
  }
  __syncthreads();
  if (t < nb) sums[t] = s[t];
}

__global__ void scan3_kernel(int* __restrict__ off, const int* __restrict__ sums,
                             int n, int total) {
  int i = blockIdx.x * 256 + threadIdx.x;
  if (i < n) off[i] += sums[i >> 10];
  else if (i == n) off[n] = total;
}

// ---------------- CSR build, phase B: final scatter + layer-1 weights --------
// All random writes/atomics land inside one bucket's window (L2-resident).

__global__ void fscatter_kernel(const int2* __restrict__ bpairs, const int* __restrict__ off,
                                int* __restrict__ cnt2, int* __restrict__ ssrc,
                                int* __restrict__ sdst, const float2* __restrict__ esv,
                                const float2* __restrict__ edv, float2* __restrict__ wgt1,
                                int E2) {
  int e = blockIdx.x * 256 + threadIdx.x;
  if (e >= E2) return;
  int2 p = bpairs[e];
  int pos = off[p.y] + atomicAdd(&cnt2[p.y], 1);
  ssrc[pos] = p.x;
  sdst[pos] = p.y;
  float2 ev = esv[p.x];
  float2 dv = edv[p.y];
  wgt1[pos] = make_float2(__expf(LRELU(ev.x + dv.x)), __expf(LRELU(ev.y + dv.y)));
}

// ---------------- fp32 GEMM: Cb[M x BN](bf16) = A[M x 128] * W[128 x BN] ------

template <int BN, int TN>
__global__ __launch_bounds__(256) void gemm_f32_bf16out(const float* __restrict__ A,
                                                        const float* __restrict__ W,
                                                        uint16_t* __restrict__ Cb, int M) {
  constexpr int BM = 64, TM = 4, BK = 32;
  constexpr int TX = BN / TN;  // 16
  __shared__ float As[BK][BM];
  __shared__ float Ws[BK][BN];
  int tid = threadIdx.x;
  int tx = tid % TX;
  int ty = tid / TX;
  int row0 = blockIdx.x * BM;
  float acc[TM][TN] = {};
  for (int kb = 0; kb < 128; kb += BK) {
    for (int i = tid; i < BM * BK / 4; i += 256) {
      int r = i >> 3;
      int k4 = i & 7;
      float4 v = make_float4(0.f, 0.f, 0.f, 0.f);
      if (row0 + r < M)
        v = *reinterpret_cast<const float4*>(A + (size_t)(row0 + r) * 128 + kb + k4 * 4);
      As[k4 * 4 + 0][r] = v.x;
      As[k4 * 4 + 1][r] = v.y;
      As[k4 * 4 + 2][r] = v.z;
      As[k4 * 4 + 3][r] = v.w;
    }
    for (int i = tid; i < BK * BN / 4; i += 256) {
      reinterpret_cast<float4*>(&Ws[0][0])[i] =
          *reinterpret_cast<const float4*>(W + (size_t)kb * BN + i * 4);
    }
    __syncthreads();
#pragma unroll
    for (int k = 0; k < BK; ++k) {
      float a[TM], b[TN];
#pragma unroll
      for (int i = 0; i < TM; ++i) a[i] = As[k][ty * TM + i];
#pragma unroll
      for (int j = 0; j < TN; ++j) b[j] = Ws[k][tx * TN + j];
#pragma unroll
      for (int i = 0; i < TM; ++i)
#pragma unroll
        for (int j = 0; j < TN; ++j) acc[i][j] = fmaf(a[i], b[j], acc[i][j]);
    }
    __syncthreads();
  }
#pragma unroll
  for (int i = 0; i < TM; ++i) {
    int r = row0 + ty * TM + i;
    if (r < M) {
      uint32_t pk[TN / 2];
#pragma unroll
      for (int j = 0; j < TN; j += 2)
        pk[j / 2] = (uint32_t)f2bf(acc[i][j]) | ((uint32_t)f2bf(acc[i][j + 1]) << 16);
      uint32_t* dst = reinterpret_cast<uint32_t*>(Cb + (size_t)r * BN + tx * TN);
#pragma unroll
      for (int j = 0; j < TN / 2; ++j) dst[j] = pk[j];
    }
  }
}

// ---------------- attention scores (per-node dot products, bf16 h) ------------

__global__ void escore1_kernel(const uint16_t* __restrict__ h, const float* __restrict__ a_src,
                               const float* __restrict__ a_dst, float* __restrict__ es,
                               float* __restrict__ ed, int n) {
  int w = (blockIdx.x * 256 + threadIdx.x) >> 6;
  int lane = threadIdx.x & 63;
  if (w >= n) return;
  float v0 = bf2f(h[(size_t)w * 128 + lane]);
  float v1 = bf2f(h[(size_t)w * 128 + 64 + lane]);
  float s0 = v0 * a_src[lane];
  float s1 = v1 * a_src[64 + lane];
  float d0 = v0 * a_dst[lane];
  float d1 = v1 * a_dst[64 + lane];
  for (int o = 32; o; o >>= 1) {
    s0 += __shfl_down(s0, o);
    s1 += __shfl_down(s1, o);
    d0 += __shfl_down(d0, o);
    d1 += __shfl_down(d1, o);
  }
  if (lane == 0) {
    es[w * 2] = s0; es[w * 2 + 1] = s1;
    ed[w * 2] = d0; ed[w * 2 + 1] = d1;
  }
}

__global__ void escore2_kernel(const uint16_t* __restrict__ h, const float* __restrict__ a_src,
                               const float* __restrict__ a_dst, float* __restrict__ es,
                               float* __restrict__ ed, int n) {
  int w = (blockIdx.x * 256 + threadIdx.x) >> 6;
  int lane = threadIdx.x & 63;
  if (w >= n) return;
  float v = bf2f(h[(size_t)w * 64 + lane]);
  float s = v * a_src[lane];
  float d = v * a_dst[lane];
  for (int o = 32; o; o >>= 1) {
    s += __shfl_down(s, o);
    d += __shfl_down(d, o);
  }
  if (lane == 0) { es[w] = s; ed[w] = d; }
}

// ---------------- layer-2 edge weights (edge-parallel, coalesced) -------------

__global__ void wprep2_kernel(const float* __restrict__ es, const float* __restrict__ ed,
                              const int* __restrict__ ssrc, const int* __restrict__ sdst,
                              float* __restrict__ wgt, int E2) {
  int e = blockIdx.x * 256 + threadIdx.x;
  if (e >= E2) return;
  int s = ssrc[e], d = sdst[e];
  wgt[e] = __expf(LRELU(es[s] + ed[d]));
}

// ---------------- aggregation (wave per dst node, raw weights + in-reg den) ---

__global__ void agg1_kernel(const uint32_t* __restrict__ hv, const float2* __restrict__ wgt,
                            const int* __restrict__ off, const int* __restrict__ ssrc,
                            const float* __restrict__ b, float* __restrict__ out, int n) {
  int w = __builtin_amdgcn_readfirstlane((blockIdx.x * 256 + threadIdx.x) >> 6);
  int lane = threadIdx.x & 63;
  if (w >= n) return;
  bool hi = lane >= 32;  // head 1
  float ax = 0.f, ay = 0.f, den = 0.f;
  int e0 = off[w], e1 = off[w + 1];
  int e = e0;
  for (; e + 8 <= e1; e += 8) {
    int s[8];
    float2 wv[8];
    uint32_t g[8];
#pragma unroll
    for (int u = 0; u < 8; ++u) { s[u] = ssrc[e + u]; wv[u] = wgt[e + u]; }
#pragma unroll
    for (int u = 0; u < 8; ++u) g[u] = hv[(size_t)s[u] * 64 + lane];
#pragma unroll
    for (int u = 0; u < 8; ++u) {
      float a = hi ? wv[u].y : wv[u].x;
      den += a;
      ax = fmaf(a, __uint_as_float(g[u] << 16), ax);
      ay = fmaf(a, __uint_as_float(g[u] & 0xffff0000u), ay);
    }
  }
  for (; e + 4 <= e1; e += 4) {
    int s[4];
    float2 wv[4];
    uint32_t g[4];
#pragma unroll
    for (int u = 0; u < 4; ++u) { s[u] = ssrc[e + u]; wv[u] = wgt[e + u]; }
#pragma unroll
    for (int u = 0; u < 4; ++u) g[u] = hv[(size_t)s[u] * 64 + lane];
#pragma unroll
    for (int u = 0; u < 4; ++u) {
      float a = hi ? wv[u].y : wv[u].x;
      den += a;
      ax = fmaf(a, __uint_as_float(g[u] << 16), ax);
      ay = fmaf(a, __uint_as_float(g[u] & 0xffff0000u), ay);
    }
  }
  for (; e < e1; ++e) {
    int s = ssrc[e];
    float2 wv = wgt[e];
    uint32_t g = hv[(size_t)s * 64 + lane];
    float a = hi ? wv.y : wv.x;
    den += a;
    ax = fmaf(a, __uint_as_float(g << 16), ax);
    ay = fmaf(a, __uint_as_float(g & 0xffff0000u), ay);
  }
  float inv = 1.0f / den;
  float2 bb = reinterpret_cast<const float2*>(b)[lane];
  float2 o2 = make_float2(fmaxf(fmaf(ax, inv, bb.x), 0.f),
                          fmaxf(fmaf(ay, inv, bb.y), 0.f));  // ReLU
  reinterpret_cast<float2*>(out)[(size_t)w * 64 + lane] = o2;
}

__global__ void agg2_kernel(const uint16_t* __restrict__ h, const float* __restrict__ wgt,
                            const int* __restrict__ off, const int* __restrict__ ssrc,
                            const float* __restrict__ b, float* __restrict__ out, int n) {
  int w = __builtin_amdgcn_readfirstlane((blockIdx.x * 256 + threadIdx.x) >> 6);
  int lane = threadIdx.x & 63;
  if (w >= n) return;
  float acc = 0.f, den = 0.f;
  int e0 = off[w], e1 = off[w + 1];
  int e = e0;
  for (; e + 8 <= e1; e += 8) {
    int s[8];
    float wv[8];
    uint16_t g[8];
#pragma unroll
    for (int u = 0; u < 8; ++u) { s[u] = ssrc[e + u]; wv[u] = wgt[e + u]; }
#pragma unroll
    for (int u = 0; u < 8; ++u) g[u] = h[(size_t)s[u] * 64 + lane];
#pragma unroll
    for (int u = 0; u < 8; ++u) { den += wv[u]; acc = fmaf(wv[u], bf2f(g[u]), acc); }
  }
  for (; e + 4 <= e1; e += 4) {
    int s[4];
    float wv[4];
    uint16_t g[4];
#pragma unroll
    for (int u = 0; u < 4; ++u) { s[u] = ssrc[e + u]; wv[u] = wgt[e + u]; }
#pragma unroll
    for (int u = 0; u < 4; ++u) g[u] = h[(size_t)s[u] * 64 + lane];
#pragma unroll
    for (int u = 0; u < 4; ++u) { den += wv[u]; acc = fmaf(wv[u], bf2f(g[u]), acc); }
  }
  for (; e < e1; ++e) {
    float wv = wgt[e];
    den += wv;
    acc = fmaf(wv, bf2f(h[(size_t)ssrc[e] * 64 + lane]), acc);
  }
  out[(size_t)w * 64 + lane] = acc / den + b[lane];    // no ReLU after layer 2
}

// ---------------- pooling + MLP ----------------

__global__ void pool_kernel(const float* __restrict__ x, const int* __restrict__ batch,
                            float* __restrict__ pooled, float* __restrict__ cnt, int n) {
  int w = (blockIdx.x * 256 + threadIdx.x) >> 6;
  int lane = threadIdx.x & 63;
  int n0 = w * 64;
  if (n0 >= n) return;
  int n1 = min(n, n0 + 64);
  float acc = 0.f;
  int cur = batch[n0];
  int run = 0;
  for (int i = n0; i < n1; ++i) {
    int g = batch[i];
    if (g != cur) {
      atomicAdd(&pooled[cur * 64 + lane], acc);
      if (lane == 0) atomicAdd(&cnt[cur], (float)run);
      acc = 0.f; run = 0; cur = g;
    }
    acc += x[(size_t)i * 64 + lane];
    ++run;
  }
  atomicAdd(&pooled[cur * 64 + lane], acc);
  if (lane == 0) atomicAdd(&cnt[cur], (float)run);
}

__global__ void mlp1_kernel(const float* __restrict__ pooled, const float* __restrict__ cnt,
                            const float* __restrict__ dw1, const float* __restrict__ db1,
                            float* __restrict__ z) {
  int g = blockIdx.x;
  int c = threadIdx.x;  // 64
  __shared__ float P[64];
  float inv = 1.0f / fmaxf(cnt[g], 1.0f);
  P[c] = pooled[g * 64 + c] * inv;
  __syncthreads();
  float s = db1[c];
#pragma unroll
  for (int k = 0; k < 64; ++k) s = fmaf(P[k], dw1[k * 64 + c], s);
  z[g * 64 + c] = fmaxf(s, 0.f);
}

__global__ void mlp2_kernel(const float* __restrict__ z, const float* __restrict__ dw2,
                            const float* __restrict__ db2, float* __restrict__ out) {
  int g = blockIdx.x;
  int o = threadIdx.x;  // 16
  __shared__ float Z[64];
  for (int i = o; i < 64; i += 16) Z[i] = z[g * 64 + i];
  __syncthreads();
  float s = db2[o];
#pragma unroll
  for (int c = 0; c < 64; ++c) s = fmaf(Z[c], dw2[c * 16 + o], s);
  out[g * 16 + o] = s;
}

// ---------------- launch ----------------

extern "C" void kernel_launch(void* const* d_in, const int* in_sizes, int n_in,
                              void* d_out, int out_size, void* d_ws, size_t ws_size,
                              hipStream_t stream) {
  const float* x      = (const float*)d_in[0];
  const int*   ei     = (const int*)d_in[1];
  const int*   batch  = (const int*)d_in[2];
  const float* W1     = (const float*)d_in[3];
  const float* a_src1 = (const float*)d_in[4];
  const float* a_dst1 = (const float*)d_in[5];
  const float* b1     = (const float*)d_in[6];
  const float* W2     = (const float*)d_in[7];
  const float* a_src2 = (const float*)d_in[8];
  const float* a_dst2 = (const float*)d_in[9];
  const float* b2     = (const float*)d_in[10];
  const float* dw1    = (const float*)d_in[11];
  const float* db1    = (const float*)d_in[12];
  const float* dw2    = (const float*)d_in[13];
  const float* db2    = (const float*)d_in[14];
  float* out = (float*)d_out;

  const int N = in_sizes[2];
  const int E = in_sizes[1] / 2;
  const int E2 = E + N;
  const int G = out_size / 16;

  // bucket shift: smallest shift with <=128 buckets
  int shift = 0;
  while ((N >> shift) >= 128) ++shift;
  const int NB = ((N - 1) >> shift) + 1;

  char* ws = (char*)d_ws;
  size_t o = 0;
  auto alloc = [&](size_t bytes) {
    void* p = ws + o;
    o = (o + bytes + 255) & ~(size_t)255;
    return p;
  };
  int*      degcnt = (int*)alloc((size_t)2 * N * 4);   // deg | cnt2
  int*      deg    = degcnt;
  int*      cnt2   = degcnt + N;
  int*      off    = (int*)alloc((size_t)(N + 1) * 4);
  int*      sums   = (int*)alloc(1024);
  int*      bcnt   = (int*)alloc(128 * 4);
  int*      boff   = (int*)alloc(132 * 4);
  int*      bcur   = (int*)alloc(128 * 4);
  int2*     bpairs = (int2*)alloc((size_t)E2 * 8);
  int*      ssrc   = (int*)alloc((size_t)E2 * 4);
  int*      sdst   = (int*)alloc((size_t)E2 * 4);
  float*    es1    = (float*)alloc((size_t)N * 2 * 4);
  float*    ed1    = (float*)alloc((size_t)N * 2 * 4);
  float*    es2    = (float*)alloc((size_t)N * 4);
  float*    ed2    = (float*)alloc((size_t)N * 4);
  float2*   wgt1   = (float2*)alloc((size_t)E2 * 8);
  float*    wgt2   = (float*)alloc((size_t)E2 * 4);
  float*    pooled = (float*)alloc((size_t)G * 64 * 4);
  float*    cntf   = (float*)alloc((size_t)G * 4);
  float*    zbuf   = (float*)alloc((size_t)G * 64 * 4);
  uint16_t* hb1    = (uint16_t*)alloc((size_t)N * 128 * 2);  // bf16 h1
  uint16_t* hb2    = (uint16_t*)alloc((size_t)N * 64 * 2);   // bf16 h2
  float*    out1   = (float*)alloc((size_t)N * 128 * 4);
  float*    out2   = (float*)alloc((size_t)N * 64 * 4);

  hipMemsetAsync(degcnt, 0, (size_t)2 * N * 4, stream);
  hipMemsetAsync(bcnt, 0, 128 * 4, stream);
  hipMemsetAsync(pooled, 0, (size_t)G * 64 * 4, stream);
  hipMemsetAsync(cntf, 0, (size_t)G * 4, stream);

  int gM = (N + 63) / 64;
  int gW = (N + 3) / 4;
  int gE2 = (E2 + 255) / 256;
  int gCH = (E2 + 2047) / 2048;

  // ---- layer-1 GEMM + scores (independent of CSR) ----
  gemm_f32_bf16out<128, 8><<<gM, 256, 0, stream>>>(x, W1, hb1, N);
  escore1_kernel<<<gW, 256, 0, stream>>>(hb1, a_src1, a_dst1, es1, ed1, N);

  // ---- CSR build (two-phase bucket scatter) ----
  bcount_kernel<<<512, 256, 0, stream>>>(ei, bcnt, E, E2, shift, NB);
  bscan_kernel<<<1, 64, 0, stream>>>(bcnt, boff, bcur, NB);
  bscatter_kernel<<<gCH, 256, 0, stream>>>(ei, bcur, bpairs, E, E2, shift);
  deghist_kernel<<<gE2, 256, 0, stream>>>(bpairs, deg, E2);
  int nbs = (N + 1023) / 1024;
  scan1_kernel<<<nbs, 256, 0, stream>>>(deg, off, sums, N);
  scan2_kernel<<<1, 256, 0, stream>>>(sums, nbs);
  scan3_kernel<<<(N + 256) / 256, 256, 0, stream>>>(off, sums, N, E2);
  fscatter_kernel<<<gE2, 256, 0, stream>>>(bpairs, off, cnt2, ssrc, sdst,
                                           (const float2*)es1, (const float2*)ed1,
                                           wgt1, E2);

  // ---- layer 1 aggregation ----
  agg1_kernel<<<gW, 256, 0, stream>>>((const uint32_t*)hb1, wgt1, off, ssrc, b1, out1, N);

  // ---- layer 2 ----
  gemm_f32_bf16out<64, 4><<<gM, 256, 0, stream>>>(out1, W2, hb2, N);
  escore2_kernel<<<gW, 256, 0, stream>>>(hb2, a_src2, a_dst2, es2, ed2, N);
  wprep2_kernel<<<gE2, 256, 0, stream>>>(es2, ed2, ssrc, sdst, wgt2, E2);
  agg2_kernel<<<gW, 256, 0, stream>>>(hb2, wgt2, off, ssrc, b2, out2, N);

  // ---- pool + MLP ----
  int nwPool = (N + 63) / 64;
  pool_kernel<<<(nwPool + 3) / 4, 256, 0, stream>>>(out2, batch, pooled, cntf, N);
  mlp1_kernel<<<G, 64, 0, stream>>>(pooled, cntf, dw1, db1, zbuf);
  mlp2_kernel<<<G, 16, 0, stream>>>(zbuf, dw2, db2, out);
}

// Round 5
// 537.394 us; speedup vs baseline: 1.4662x; 1.0529x over previous
//
#include <hip/hip_runtime.h>
#include <stdint.h>

// ---------------------------------------------------------------------------
// SpatialGNN: 2x GATConv (2 heads -> 1 head), mean-pool per graph, MLP.
// R5: GEMMs -> bf16 MFMA (16x16x32), zero-LDS: A row-major bf16 + W^T bf16
//     give contiguous 16B fragment loads. x converted to bf16 once; agg1
//     emits bf16 out1 directly (packed dword stores). CSR build unchanged.
// ---------------------------------------------------------------------------

#define LRELU(x) ((x) > 0.f ? (x) : 0.2f * (x))

typedef short bf8 __attribute__((ext_vector_type(8)));   // 8 bf16 (4 VGPR)
typedef float f32x4 __attribute__((ext_vector_type(4))); // 4 fp32 acc

__device__ __forceinline__ uint16_t f2bf(float f) {
  uint32_t u = __float_as_uint(f);
  u += 0x7fff + ((u >> 16) & 1);   // RNE
  return (uint16_t)(u >> 16);
}
__device__ __forceinline__ float bf2f(uint16_t b) {
  return __uint_as_float(((uint32_t)b) << 16);
}
__device__ __forceinline__ uint32_t pack2bf(float a, float b) {
  return (uint32_t)f2bf(a) | ((uint32_t)f2bf(b) << 16);
}

// ---------------- dtype converts ----------------

__global__ void cvt_x_kernel(const float* __restrict__ x, uint16_t* __restrict__ xb,
                             int total8) {
  int i = (blockIdx.x * 256 + threadIdx.x);
  if (i >= total8) return;
  const float4* p = reinterpret_cast<const float4*>(x + (size_t)i * 8);
  float4 v0 = p[0], v1 = p[1];
  uint4 o;
  o.x = pack2bf(v0.x, v0.y);
  o.y = pack2bf(v0.z, v0.w);
  o.z = pack2bf(v1.x, v1.y);
  o.w = pack2bf(v1.z, v1.w);
  *reinterpret_cast<uint4*>(xb + (size_t)i * 8) = o;
}

// W [K=128 x N] fp32 -> WT [N x 128] bf16
__global__ void cvt_wt_kernel(const float* __restrict__ W, uint16_t* __restrict__ WT,
                              int N, int total) {
  int idx = blockIdx.x * 256 + threadIdx.x;
  if (idx >= total) return;
  int n = idx >> 7, k = idx & 127;
  WT[idx] = f2bf(W[(size_t)k * N + n]);
}

// ---------------- bf16 MFMA GEMM: C[M x N](bf16) = A[M x 128] * W[128 x N] ---
// Block = 256 thr = 4 waves; wave covers 32 rows (2 row-tiles of 16).
// A row-major bf16, B as W^T row-major bf16 (L1-resident). No LDS.

template <int N>
__global__ __launch_bounds__(256) void gemm_mfma(const uint16_t* __restrict__ A,
                                                 const uint16_t* __restrict__ WT,
                                                 uint16_t* __restrict__ C, int M) {
  constexpr int CT = N / 16;           // col tiles
  int wave = threadIdx.x >> 6;
  int lane = threadIdx.x & 63;
  int m16 = lane & 15;
  int quad = lane >> 4;                // 0..3
  int row_base = blockIdx.x * 128 + wave * 32;
  if (row_base >= M) return;           // M % 32 == 0 -> whole-wave guard exact
  const uint16_t* Ar0 = A + (size_t)(row_base + m16) * 128;
  const uint16_t* Ar1 = Ar0 + (size_t)16 * 128;
  f32x4 acc[2][CT] = {};
#pragma unroll
  for (int ks = 0; ks < 4; ++ks) {
    int k0 = ks * 32 + quad * 8;
    bf8 a0 = *reinterpret_cast<const bf8*>(Ar0 + k0);
    bf8 a1 = *reinterpret_cast<const bf8*>(Ar1 + k0);
#pragma unroll
    for (int c = 0; c < CT; ++c) {
      bf8 b = *reinterpret_cast<const bf8*>(WT + (size_t)(c * 16 + m16) * 128 + k0);
      acc[0][c] = __builtin_amdgcn_mfma_f32_16x16x32_bf16(a0, b, acc[0][c], 0, 0, 0);
      acc[1][c] = __builtin_amdgcn_mfma_f32_16x16x32_bf16(a1, b, acc[1][c], 0, 0, 0);
    }
  }
  // C/D layout: col = lane&15, row = quad*4 + reg   [m89-verified]
#pragma unroll
  for (int r = 0; r < 2; ++r) {
#pragma unroll
    for (int c = 0; c < CT; ++c) {
#pragma unroll
      for (int reg = 0; reg < 4; ++reg) {
        int row = row_base + r * 16 + quad * 4 + reg;
        C[(size_t)row * N + c * 16 + m16] = f2bf(acc[r][c][reg]);
      }
    }
  }
}

// ---------------- CSR build, phase A: bucket by dst>>shift ----------------

__global__ void bcount_kernel(const int* __restrict__ ei, int* __restrict__ bcnt,
                              int E, int E2, int shift, int nb) {
  __shared__ int lh[128];
  int t = threadIdx.x;
  if (t < 128) lh[t] = 0;
  __syncthreads();
  for (int e = blockIdx.x * 256 + t; e < E2; e += gridDim.x * 256) {
    int d = (e < E) ? ei[E + e] : (e - E);
    atomicAdd(&lh[d >> shift], 1);
  }
  __syncthreads();
  if (t < nb) { int v = lh[t]; if (v) atomicAdd(&bcnt[t], v); }
}

__global__ void bscan_kernel(const int* __restrict__ bcnt, int* __restrict__ boff,
                             int* __restrict__ bcur, int nb) {
  if (threadIdx.x == 0) {
    int acc = 0;
    for (int i = 0; i < nb; ++i) { boff[i] = acc; bcur[i] = acc; acc += bcnt[i]; }
    boff[nb] = acc;
  }
}

__global__ void bscatter_kernel(const int* __restrict__ ei, int* __restrict__ bcur,
                                int2* __restrict__ bpairs, int E, int E2, int shift) {
  __shared__ int lh[128];
  __shared__ int lb[128];
  int t = threadIdx.x;
  if (t < 128) lh[t] = 0;
  __syncthreads();
  int base = blockIdx.x * 2048;
  int src[8], dst[8], rk[8], bk[8];
#pragma unroll
  for (int u = 0; u < 8; ++u) {
    int e = base + u * 256 + t;
    if (e < E2) {
      int s, d;
      if (e < E) { s = ei[e]; d = ei[E + e]; } else { s = d = e - E; }
      src[u] = s; dst[u] = d; bk[u] = d >> shift;
      rk[u] = atomicAdd(&lh[bk[u]], 1);
    } else rk[u] = -1;
  }
  __syncthreads();
  if (t < 128) { int c = lh[t]; lb[t] = c ? atomicAdd(&bcur[t], c) : 0; }
  __syncthreads();
#pragma unroll
  for (int u = 0; u < 8; ++u) {
    if (rk[u] >= 0) bpairs[lb[bk[u]] + rk[u]] = make_int2(src[u], dst[u]);
  }
}

__global__ void deghist_kernel(const int2* __restrict__ bpairs, int* __restrict__ deg,
                               int E2) {
  int e = blockIdx.x * 256 + threadIdx.x;
  if (e < E2) atomicAdd(&deg[bpairs[e].y], 1);
}

// ---------------- node-level prefix scan ----------------

__global__ void scan1_kernel(const int* __restrict__ deg, int* __restrict__ off,
                             int* __restrict__ sums, int n) {
  __shared__ int s[256];
  int t = threadIdx.x;
  int base = blockIdx.x * 1024 + t * 4;
  int v0 = (base + 0 < n) ? deg[base + 0] : 0;
  int v1 = (base + 1 < n) ? deg[base + 1] : 0;
  int v2 = (base + 2 < n) ? deg[base + 2] : 0;
  int v3 = (base + 3 < n) ? deg[base + 3] : 0;
  int sum = v0 + v1 + v2 + v3;
  s[t] = sum;
  __syncthreads();
  for (int d = 1; d < 256; d <<= 1) {
    int x = (t >= d) ? s[t - d] : 0;
    __syncthreads();
    s[t] += x;
    __syncthreads();
  }
  if (t == 255) sums[blockIdx.x] = s[255];
  int run = s[t] - sum;
  if (base + 0 < n) { off[base + 0] = run; run += v0; }
  if (base + 1 < n) { off[base + 1] = run; run += v1; }
  if (base + 2 < n) { off[base + 2] = run; run += v2; }
  if (base + 3 < n) { off[base + 3] = run; }
}

__global__ void scan2_kernel(int* __restrict__ sums, int nb) {
  __shared__ int s[256];
  int t = threadIdx.x;
  s[t] = (t < nb) ? sums[t] : 0;
  __syncthreads();
  if (t == 0) {
    int acc = 0;
    for (int i = 0; i < nb; ++i) { int v = s[i]; s[i] = acc; acc += v; }
  }
  __syncthreads();
  if (t < nb) sums[t] = s[t];
}

__global__ void scan3_kernel(int* __restrict__ off, const int* __restrict__ sums,
                             int n, int total) {
  int i = blockIdx.x * 256 + threadIdx.x;
  if (i < n) off[i] += sums[i >> 10];
  else if (i == n) off[n] = total;
}

// ---------------- CSR phase B: final scatter + layer-1 weights ----------------

__global__ void fscatter_kernel(const int2* __restrict__ bpairs, const int* __restrict__ off,
                                int* __restrict__ cnt2, int* __restrict__ ssrc,
                                int* __restrict__ sdst, const float2* __restrict__ esv,
                                const float2* __restrict__ edv, float2* __restrict__ wgt1,
                                int E2) {
  int e = blockIdx.x * 256 + threadIdx.x;
  if (e >= E2) return;
  int2 p = bpairs[e];
  int pos = off[p.y] + atomicAdd(&cnt2[p.y], 1);
  ssrc[pos] = p.x;
  sdst[pos] = p.y;
  float2 ev = esv[p.x];
  float2 dv = edv[p.y];
  wgt1[pos] = make_float2(__expf(LRELU(ev.x + dv.x)), __expf(LRELU(ev.y + dv.y)));
}

// ---------------- attention scores (per-node dot products, bf16 h) ------------

__global__ void escore1_kernel(const uint16_t* __restrict__ h, const float* __restrict__ a_src,
                               const float* __restrict__ a_dst, float* __restrict__ es,
                               float* __restrict__ ed, int n) {
  int w = (blockIdx.x * 256 + threadIdx.x) >> 6;
  int lane = threadIdx.x & 63;
  if (w >= n) return;
  float v0 = bf2f(h[(size_t)w * 128 + lane]);
  float v1 = bf2f(h[(size_t)w * 128 + 64 + lane]);
  float s0 = v0 * a_src[lane];
  float s1 = v1 * a_src[64 + lane];
  float d0 = v0 * a_dst[lane];
  float d1 = v1 * a_dst[64 + lane];
  for (int o = 32; o; o >>= 1) {
    s0 += __shfl_down(s0, o);
    s1 += __shfl_down(s1, o);
    d0 += __shfl_down(d0, o);
    d1 += __shfl_down(d1, o);
  }
  if (lane == 0) {
    es[w * 2] = s0; es[w * 2 + 1] = s1;
    ed[w * 2] = d0; ed[w * 2 + 1] = d1;
  }
}

__global__ void escore2_kernel(const uint16_t* __restrict__ h, const float* __restrict__ a_src,
                               const float* __restrict__ a_dst, float* __restrict__ es,
                               float* __restrict__ ed, int n) {
  int w = (blockIdx.x * 256 + threadIdx.x) >> 6;
  int lane = threadIdx.x & 63;
  if (w >= n) return;
  float v = bf2f(h[(size_t)w * 64 + lane]);
  float s = v * a_src[lane];
  float d = v * a_dst[lane];
  for (int o = 32; o; o >>= 1) {
    s += __shfl_down(s, o);
    d += __shfl_down(d, o);
  }
  if (lane == 0) { es[w] = s; ed[w] = d; }
}

// ---------------- layer-2 edge weights (edge-parallel, coalesced) -------------

__global__ void wprep2_kernel(const float* __restrict__ es, const float* __restrict__ ed,
                              const int* __restrict__ ssrc, const int* __restrict__ sdst,
                              float* __restrict__ wgt, int E2) {
  int e = blockIdx.x * 256 + threadIdx.x;
  if (e >= E2) return;
  int s = ssrc[e], d = sdst[e];
  wgt[e] = __expf(LRELU(es[s] + ed[d]));
}

// ---------------- aggregation (wave per dst node, raw wgts + in-reg denom) ----

__global__ void agg1_kernel(const uint32_t* __restrict__ hv, const float2* __restrict__ wgt,
                            const int* __restrict__ off, const int* __restrict__ ssrc,
                            const float* __restrict__ b, uint32_t* __restrict__ outb, int n) {
  int w = __builtin_amdgcn_readfirstlane((blockIdx.x * 256 + threadIdx.x) >> 6);
  int lane = threadIdx.x & 63;
  if (w >= n) return;
  bool hi = lane >= 32;  // head 1
  float ax = 0.f, ay = 0.f, den = 0.f;
  int e0 = off[w], e1 = off[w + 1];
  int e = e0;
  for (; e + 8 <= e1; e += 8) {
    int s[8];
    float2 wv[8];
    uint32_t g[8];
#pragma unroll
    for (int u = 0; u < 8; ++u) { s[u] = ssrc[e + u]; wv[u] = wgt[e + u]; }
#pragma unroll
    for (int u = 0; u < 8; ++u) g[u] = hv[(size_t)s[u] * 64 + lane];
#pragma unroll
    for (int u = 0; u < 8; ++u) {
      float a = hi ? wv[u].y : wv[u].x;
      den += a;
      ax = fmaf(a, __uint_as_float(g[u] << 16), ax);
      ay = fmaf(a, __uint_as_float(g[u] & 0xffff0000u), ay);
    }
  }
  for (; e + 4 <= e1; e += 4) {
    int s[4];
    float2 wv[4];
    uint32_t g[4];
#pragma unroll
    for (int u = 0; u < 4; ++u) { s[u] = ssrc[e + u]; wv[u] = wgt[e + u]; }
#pragma unroll
    for (int u = 0; u < 4; ++u) g[u] = hv[(size_t)s[u] * 64 + lane];
#pragma unroll
    for (int u = 0; u < 4; ++u) {
      float a = hi ? wv[u].y : wv[u].x;
      den += a;
      ax = fmaf(a, __uint_as_float(g[u] << 16), ax);
      ay = fmaf(a, __uint_as_float(g[u] & 0xffff0000u), ay);
    }
  }
  for (; e < e1; ++e) {
    int s = ssrc[e];
    float2 wv = wgt[e];
    uint32_t g = hv[(size_t)s * 64 + lane];
    float a = hi ? wv.y : wv.x;
    den += a;
    ax = fmaf(a, __uint_as_float(g << 16), ax);
    ay = fmaf(a, __uint_as_float(g & 0xffff0000u), ay);
  }
  float inv = 1.0f / den;
  float2 bb = reinterpret_cast<const float2*>(b)[lane];
  float o0 = fmaxf(fmaf(ax, inv, bb.x), 0.f);   // ReLU
  float o1 = fmaxf(fmaf(ay, inv, bb.y), 0.f);
  outb[(size_t)w * 64 + lane] = pack2bf(o0, o1);  // bf16 row of 128 for GEMM2
}

__global__ void agg2_kernel(const uint16_t* __restrict__ h, const float* __restrict__ wgt,
                            const int* __restrict__ off, const int* __restrict__ ssrc,
                            const float* __restrict__ b, float* __restrict__ out, int n) {
  int w = __builtin_amdgcn_readfirstlane((blockIdx.x * 256 + threadIdx.x) >> 6);
  int lane = threadIdx.x & 63;
  if (w >= n) return;
  float acc = 0.f, den = 0.f;
  int e0 = off[w], e1 = off[w + 1];
  int e = e0;
  for (; e + 8 <= e1; e += 8) {
    int s[8];
    float wv[8];
    uint16_t g[8];
#pragma unroll
    for (int u = 0; u < 8; ++u) { s[u] = ssrc[e + u]; wv[u] = wgt[e + u]; }
#pragma unroll
    for (int u = 0; u < 8; ++u) g[u] = h[(size_t)s[u] * 64 + lane];
#pragma unroll
    for (int u = 0; u < 8; ++u) { den += wv[u]; acc = fmaf(wv[u], bf2f(g[u]), acc); }
  }
  for (; e + 4 <= e1; e += 4) {
    int s[4];
    float wv[4];
    uint16_t g[4];
#pragma unroll
    for (int u = 0; u < 4; ++u) { s[u] = ssrc[e + u]; wv[u] = wgt[e + u]; }
#pragma unroll
    for (int u = 0; u < 4; ++u) g[u] = h[(size_t)s[u] * 64 + lane];
#pragma unroll
    for (int u = 0; u < 4; ++u) { den += wv[u]; acc = fmaf(wv[u], bf2f(g[u]), acc); }
  }
  for (; e < e1; ++e) {
    float wv = wgt[e];
    den += wv;
    acc = fmaf(wv, bf2f(h[(size_t)ssrc[e] * 64 + lane]), acc);
  }
  out[(size_t)w * 64 + lane] = acc / den + b[lane];    // no ReLU after layer 2
}

// ---------------- pooling + MLP ----------------

__global__ void pool_kernel(const float* __restrict__ x, const int* __restrict__ batch,
                            float* __restrict__ pooled, float* __restrict__ cnt, int n) {
  int w = (blockIdx.x * 256 + threadIdx.x) >> 6;
  int lane = threadIdx.x & 63;
  int n0 = w * 64;
  if (n0 >= n) return;
  int n1 = min(n, n0 + 64);
  float acc = 0.f;
  int cur = batch[n0];
  int run = 0;
  for (int i = n0; i < n1; ++i) {
    int g = batch[i];
    if (g != cur) {
      atomicAdd(&pooled[cur * 64 + lane], acc);
      if (lane == 0) atomicAdd(&cnt[cur], (float)run);
      acc = 0.f; run = 0; cur = g;
    }
    acc += x[(size_t)i * 64 + lane];
    ++run;
  }
  atomicAdd(&pooled[cur * 64 + lane], acc);
  if (lane == 0) atomicAdd(&cnt[cur], (float)run);
}

__global__ void mlp1_kernel(const float* __restrict__ pooled, const float* __restrict__ cnt,
                            const float* __restrict__ dw1, const float* __restrict__ db1,
                            float* __restrict__ z) {
  int g = blockIdx.x;
  int c = threadIdx.x;  // 64
  __shared__ float P[64];
  float inv = 1.0f / fmaxf(cnt[g], 1.0f);
  P[c] = pooled[g * 64 + c] * inv;
  __syncthreads();
  float s = db1[c];
#pragma unroll
  for (int k = 0; k < 64; ++k) s = fmaf(P[k], dw1[k * 64 + c], s);
  z[g * 64 + c] = fmaxf(s, 0.f);
}

__global__ void mlp2_kernel(const float* __restrict__ z, const float* __restrict__ dw2,
                            const float* __restrict__ db2, float* __restrict__ out) {
  int g = blockIdx.x;
  int o = threadIdx.x;  // 16
  __shared__ float Z[64];
  for (int i = o; i < 64; i += 16) Z[i] = z[g * 64 + i];
  __syncthreads();
  float s = db2[o];
#pragma unroll
  for (int c = 0; c < 64; ++c) s = fmaf(Z[c], dw2[c * 16 + o], s);
  out[g * 16 + o] = s;
}

// ---------------- launch ----------------

extern "C" void kernel_launch(void* const* d_in, const int* in_sizes, int n_in,
                              void* d_out, int out_size, void* d_ws, size_t ws_size,
                              hipStream_t stream) {
  const float* x      = (const float*)d_in[0];
  const int*   ei     = (const int*)d_in[1];
  const int*   batch  = (const int*)d_in[2];
  const float* W1     = (const float*)d_in[3];
  const float* a_src1 = (const float*)d_in[4];
  const float* a_dst1 = (const float*)d_in[5];
  const float* b1     = (const float*)d_in[6];
  const float* W2     = (const float*)d_in[7];
  const float* a_src2 = (const float*)d_in[8];
  const float* a_dst2 = (const float*)d_in[9];
  const float* b2     = (const float*)d_in[10];
  const float* dw1    = (const float*)d_in[11];
  const float* db1    = (const float*)d_in[12];
  const float* dw2    = (const float*)d_in[13];
  const float* db2    = (const float*)d_in[14];
  float* out = (float*)d_out;

  const int N = in_sizes[2];
  const int E = in_sizes[1] / 2;
  const int E2 = E + N;
  const int G = out_size / 16;

  int shift = 0;
  while ((N >> shift) >= 128) ++shift;
  const int NB = ((N - 1) >> shift) + 1;

  char* ws = (char*)d_ws;
  size_t o = 0;
  auto alloc = [&](size_t bytes) {
    void* p = ws + o;
    o = (o + bytes + 255) & ~(size_t)255;
    return p;
  };
  int*      degcnt = (int*)alloc((size_t)2 * N * 4);   // deg | cnt2
  int*      deg    = degcnt;
  int*      cnt2   = degcnt + N;
  int*      off    = (int*)alloc((size_t)(N + 1) * 4);
  int*      sums   = (int*)alloc(1024);
  int*      bcnt   = (int*)alloc(128 * 4);
  int*      boff   = (int*)alloc(132 * 4);
  int*      bcur   = (int*)alloc(128 * 4);
  int2*     bpairs = (int2*)alloc((size_t)E2 * 8);
  int*      ssrc   = (int*)alloc((size_t)E2 * 4);
  int*      sdst   = (int*)alloc((size_t)E2 * 4);
  float*    es1    = (float*)alloc((size_t)N * 2 * 4);
  float*    ed1    = (float*)alloc((size_t)N * 2 * 4);
  float*    es2    = (float*)alloc((size_t)N * 4);
  float*    ed2    = (float*)alloc((size_t)N * 4);
  float2*   wgt1   = (float2*)alloc((size_t)E2 * 8);
  float*    wgt2   = (float*)alloc((size_t)E2 * 4);
  float*    pooled = (float*)alloc((size_t)G * 64 * 4);
  float*    cntf   = (float*)alloc((size_t)G * 4);
  float*    zbuf   = (float*)alloc((size_t)G * 64 * 4);
  uint16_t* xb     = (uint16_t*)alloc((size_t)N * 128 * 2);  // bf16 x
  uint16_t* wt1b   = (uint16_t*)alloc((size_t)128 * 128 * 2);
  uint16_t* wt2b   = (uint16_t*)alloc((size_t)64 * 128 * 2);
  uint16_t* hb1    = (uint16_t*)alloc((size_t)N * 128 * 2);  // bf16 h1
  uint16_t* hb2    = (uint16_t*)alloc((size_t)N * 64 * 2);   // bf16 h2
  uint32_t* out1b  = (uint32_t*)alloc((size_t)N * 64 * 4);   // bf16 out1 (packed)
  float*    out2   = (float*)alloc((size_t)N * 64 * 4);

  hipMemsetAsync(degcnt, 0, (size_t)2 * N * 4, stream);
  hipMemsetAsync(bcnt, 0, 128 * 4, stream);
  hipMemsetAsync(pooled, 0, (size_t)G * 64 * 4, stream);
  hipMemsetAsync(cntf, 0, (size_t)G * 4, stream);

  int gM = (N + 127) / 128;            // mfma gemm blocks (128 rows each)
  int gW = (N + 3) / 4;
  int gE2 = (E2 + 255) / 256;
  int gCH = (E2 + 2047) / 2048;

  // ---- converts (x, W^T) ----
  int total8 = (N * 128) / 8;
  cvt_x_kernel<<<(total8 + 255) / 256, 256, 0, stream>>>(x, xb, total8);
  cvt_wt_kernel<<<(128 * 128 + 255) / 256, 256, 0, stream>>>(W1, wt1b, 128, 128 * 128);
  cvt_wt_kernel<<<(64 * 128 + 255) / 256, 256, 0, stream>>>(W2, wt2b, 64, 64 * 128);

  // ---- layer-1 GEMM + scores (independent of CSR) ----
  gemm_mfma<128><<<gM, 256, 0, stream>>>(xb, wt1b, hb1, N);
  escore1_kernel<<<gW, 256, 0, stream>>>(hb1, a_src1, a_dst1, es1, ed1, N);

  // ---- CSR build (two-phase bucket scatter) ----
  bcount_kernel<<<512, 256, 0, stream>>>(ei, bcnt, E, E2, shift, NB);
  bscan_kernel<<<1, 64, 0, stream>>>(bcnt, boff, bcur, NB);
  bscatter_kernel<<<gCH, 256, 0, stream>>>(ei, bcur, bpairs, E, E2, shift);
  deghist_kernel<<<gE2, 256, 0, stream>>>(bpairs, deg, E2);
  int nbs = (N + 1023) / 1024;
  scan1_kernel<<<nbs, 256, 0, stream>>>(deg, off, sums, N);
  scan2_kernel<<<1, 256, 0, stream>>>(sums, nbs);
  scan3_kernel<<<(N + 256) / 256, 256, 0, stream>>>(off, sums, N, E2);
  fscatter_kernel<<<gE2, 256, 0, stream>>>(bpairs, off, cnt2, ssrc, sdst,
                                           (const float2*)es1, (const float2*)ed1,
                                           wgt1, E2);

  // ---- layer 1 aggregation (emits bf16 rows for GEMM2) ----
  agg1_kernel<<<gW, 256, 0, stream>>>((const uint32_t*)hb1, wgt1, off, ssrc, b1, out1b, N);

  // ---- layer 2 ----
  gemm_mfma<64><<<gM, 256, 0, stream>>>((const uint16_t*)out1b, wt2b, hb2, N);
  escore2_kernel<<<gW, 256, 0, stream>>>(hb2, a_src2, a_dst2, es2, ed2, N);
  wprep2_kernel<<<gE2, 256, 0, stream>>>(es2, ed2, ssrc, sdst, wgt2, E2);
  agg2_kernel<<<gW, 256, 0, stream>>>(hb2, wgt2, off, ssrc, b2, out2, N);

  // ---- pool + MLP ----
  int nwPool = (N + 63) / 64;
  pool_kernel<<<(nwPool + 3) / 4, 256, 0, stream>>>(out2, batch, pooled, cntf, N);
  mlp1_kernel<<<G, 64, 0, stream>>>(pooled, cntf, dw1, db1, zbuf);
  mlp2_kernel<<<G, 16, 0, stream>>>(zbuf, dw2, db2, out);
}

// Round 6
// 472.409 us; speedup vs baseline: 1.6679x; 1.1376x over previous
//
#include <hip/hip_runtime.h>
#include <stdint.h>

// ---------------------------------------------------------------------------
// SpatialGNN: 2x GATConv (2 heads -> 1 head), mean-pool per graph, MLP.
// R6: CSR finalization = one block per bucket (LDS histogram + local scan),
//     exploiting off[bucket] == boff[bucket]. Kills 7x write amplification
//     (per-XCD L2 line thrash) of the atomic fscatter. Global deg/scan
//     kernels deleted. MFMA GEMMs + bf16 features unchanged.
// ---------------------------------------------------------------------------

#define LRELU(x) ((x) > 0.f ? (x) : 0.2f * (x))

typedef short bf8 __attribute__((ext_vector_type(8)));   // 8 bf16 (4 VGPR)
typedef float f32x4 __attribute__((ext_vector_type(4))); // 4 fp32 acc

__device__ __forceinline__ uint16_t f2bf(float f) {
  uint32_t u = __float_as_uint(f);
  u += 0x7fff + ((u >> 16) & 1);   // RNE
  return (uint16_t)(u >> 16);
}
__device__ __forceinline__ float bf2f(uint16_t b) {
  return __uint_as_float(((uint32_t)b) << 16);
}
__device__ __forceinline__ uint32_t pack2bf(float a, float b) {
  return (uint32_t)f2bf(a) | ((uint32_t)f2bf(b) << 16);
}

// ---------------- dtype converts ----------------

__global__ void cvt_x_kernel(const float* __restrict__ x, uint16_t* __restrict__ xb,
                             int total8) {
  int i = (blockIdx.x * 256 + threadIdx.x);
  if (i >= total8) return;
  const float4* p = reinterpret_cast<const float4*>(x + (size_t)i * 8);
  float4 v0 = p[0], v1 = p[1];
  uint4 o;
  o.x = pack2bf(v0.x, v0.y);
  o.y = pack2bf(v0.z, v0.w);
  o.z = pack2bf(v1.x, v1.y);
  o.w = pack2bf(v1.z, v1.w);
  *reinterpret_cast<uint4*>(xb + (size_t)i * 8) = o;
}

// W [K=128 x N] fp32 -> WT [N x 128] bf16
__global__ void cvt_wt_kernel(const float* __restrict__ W, uint16_t* __restrict__ WT,
                              int N, int total) {
  int idx = blockIdx.x * 256 + threadIdx.x;
  if (idx >= total) return;
  int n = idx >> 7, k = idx & 127;
  WT[idx] = f2bf(W[(size_t)k * N + n]);
}

// ---------------- bf16 MFMA GEMM: C[M x N](bf16) = A[M x 128] * W[128 x N] ---

template <int N>
__global__ __launch_bounds__(256) void gemm_mfma(const uint16_t* __restrict__ A,
                                                 const uint16_t* __restrict__ WT,
                                                 uint16_t* __restrict__ C, int M) {
  constexpr int CT = N / 16;           // col tiles
  int wave = threadIdx.x >> 6;
  int lane = threadIdx.x & 63;
  int m16 = lane & 15;
  int quad = lane >> 4;                // 0..3
  int row_base = blockIdx.x * 128 + wave * 32;
  if (row_base >= M) return;           // M % 32 == 0 -> whole-wave guard exact
  const uint16_t* Ar0 = A + (size_t)(row_base + m16) * 128;
  const uint16_t* Ar1 = Ar0 + (size_t)16 * 128;
  f32x4 acc[2][CT] = {};
#pragma unroll
  for (int ks = 0; ks < 4; ++ks) {
    int k0 = ks * 32 + quad * 8;
    bf8 a0 = *reinterpret_cast<const bf8*>(Ar0 + k0);
    bf8 a1 = *reinterpret_cast<const bf8*>(Ar1 + k0);
#pragma unroll
    for (int c = 0; c < CT; ++c) {
      bf8 b = *reinterpret_cast<const bf8*>(WT + (size_t)(c * 16 + m16) * 128 + k0);
      acc[0][c] = __builtin_amdgcn_mfma_f32_16x16x32_bf16(a0, b, acc[0][c], 0, 0, 0);
      acc[1][c] = __builtin_amdgcn_mfma_f32_16x16x32_bf16(a1, b, acc[1][c], 0, 0, 0);
    }
  }
  // C/D layout: col = lane&15, row = quad*4 + reg   [m89-verified]
#pragma unroll
  for (int r = 0; r < 2; ++r) {
#pragma unroll
    for (int c = 0; c < CT; ++c) {
#pragma unroll
      for (int reg = 0; reg < 4; ++reg) {
        int row = row_base + r * 16 + quad * 4 + reg;
        C[(size_t)row * N + c * 16 + m16] = f2bf(acc[r][c][reg]);
      }
    }
  }
}

// ---------------- CSR build, phase A: bucket by dst>>shift ----------------

__global__ void bcount_kernel(const int* __restrict__ ei, int* __restrict__ bcnt,
                              int E, int E2, int shift, int nb) {
  __shared__ int lh[512];
  int t = threadIdx.x;
  for (int i = t; i < 512; i += 256) lh[i] = 0;
  __syncthreads();
  for (int e = blockIdx.x * 256 + t; e < E2; e += gridDim.x * 256) {
    int d = (e < E) ? ei[E + e] : (e - E);
    atomicAdd(&lh[d >> shift], 1);
  }
  __syncthreads();
  for (int i = t; i < nb; i += 256) {
    int v = lh[i];
    if (v) atomicAdd(&bcnt[i], v);
  }
}

// parallel exclusive scan over nb (<=512) bucket counts
__global__ __launch_bounds__(512) void bscan_kernel(const int* __restrict__ bcnt,
                                                    int* __restrict__ boff,
                                                    int* __restrict__ bcur, int nb) {
  __shared__ int s[512];
  int t = threadIdx.x;
  int v = (t < nb) ? bcnt[t] : 0;
  s[t] = v;
  __syncthreads();
  for (int d = 1; d < 512; d <<= 1) {
    int x = (t >= d) ? s[t - d] : 0;
    __syncthreads();
    s[t] += x;
    __syncthreads();
  }
  if (t < nb) {
    int ex = s[t] - v;
    boff[t] = ex;
    bcur[t] = ex;
    if (t == nb - 1) boff[nb] = s[t];
  }
}

__global__ void bscatter_kernel(const int* __restrict__ ei, int* __restrict__ bcur,
                                int2* __restrict__ bpairs, int E, int E2, int shift,
                                int nb) {
  __shared__ int lh[512];
  __shared__ int lb[512];
  int t = threadIdx.x;
  for (int i = t; i < 512; i += 256) lh[i] = 0;
  __syncthreads();
  int base = blockIdx.x * 2048;
  int src[8], dst[8], rk[8], bk[8];
#pragma unroll
  for (int u = 0; u < 8; ++u) {
    int e = base + u * 256 + t;
    if (e < E2) {
      int s, d;
      if (e < E) { s = ei[e]; d = ei[E + e]; } else { s = d = e - E; }
      src[u] = s; dst[u] = d; bk[u] = d >> shift;
      rk[u] = atomicAdd(&lh[bk[u]], 1);
    } else rk[u] = -1;
  }
  __syncthreads();
  for (int i = t; i < nb; i += 256) {
    int c = lh[i];
    lb[i] = c ? atomicAdd(&bcur[i], c) : 0;
  }
  __syncthreads();
#pragma unroll
  for (int u = 0; u < 8; ++u) {
    if (rk[u] >= 0) bpairs[lb[bk[u]] + rk[u]] = make_int2(src[u], dst[u]);
  }
}

// ---------------- CSR phase B: one block per bucket ---------------------------
// Global offset of bucket b is boff[b]; node offsets = boff[b] + local scan.
// All random writes land in this block's contiguous output range (one XCD's L2).
// Also fuses layer-1 edge weights.

__global__ __launch_bounds__(256) void bfinal_kernel(
    const int2* __restrict__ bpairs, const int* __restrict__ boff,
    int* __restrict__ off, int* __restrict__ ssrc, int* __restrict__ sdst,
    const float2* __restrict__ esv, const float2* __restrict__ edv,
    float2* __restrict__ wgt1, int N, int E2, int shift, int NB) {
  __shared__ int lh[1024];
  __shared__ int loff[1024];
  __shared__ int tsum[256];
  int b = blockIdx.x;
  int t = threadIdx.x;
  int bsz = 1 << shift;                       // nodes per bucket (<=1024)
  int node0 = b << shift;
  int e0 = boff[b], e1 = boff[b + 1];
  for (int i = t; i < bsz; i += 256) lh[i] = 0;
  __syncthreads();
  // pass A: degree histogram in LDS
  for (int e = e0 + t; e < e1; e += 256) {
    atomicAdd(&lh[bpairs[e].y - node0], 1);
  }
  __syncthreads();
  // bucket-local exclusive scan over bsz entries (per = bsz/256 <= 4)
  int per = bsz >> 8;
  if (per < 1) per = 1;
  int basei = t * per;
  int vals[4];
  int s = 0;
#pragma unroll 4
  for (int j = 0; j < per; ++j) { vals[j] = lh[basei + j]; s += vals[j]; }
  tsum[t] = s;
  __syncthreads();
  for (int d = 1; d < 256; d <<= 1) {
    int x = (t >= d) ? tsum[t - d] : 0;
    __syncthreads();
    tsum[t] += x;
    __syncthreads();
  }
  int run = tsum[t] - s;
#pragma unroll 4
  for (int j = 0; j < per; ++j) { loff[basei + j] = run; run += vals[j]; }
  __syncthreads();
  // write node offsets (coalesced)
  for (int i = t; i < bsz; i += 256) {
    int v = node0 + i;
    if (v < N) off[v] = e0 + loff[i];
  }
  if (b == NB - 1 && t == 0) off[N] = E2;
  // pass B: rank + scatter (reuse lh as rank counters)
  for (int i = t; i < bsz; i += 256) lh[i] = 0;
  __syncthreads();
  for (int e = e0 + t; e < e1; e += 256) {
    int2 p = bpairs[e];
    int ld = p.y - node0;
    int r = atomicAdd(&lh[ld], 1);
    int pos = e0 + loff[ld] + r;
    ssrc[pos] = p.x;
    sdst[pos] = p.y;
    float2 ev = esv[p.x];
    float2 dv = edv[p.y];
    wgt1[pos] = make_float2(__expf(LRELU(ev.x + dv.x)), __expf(LRELU(ev.y + dv.y)));
  }
}

// ---------------- attention scores (per-node dot products, bf16 h) ------------

__global__ void escore1_kernel(const uint16_t* __restrict__ h, const float* __restrict__ a_src,
                               const float* __restrict__ a_dst, float* __restrict__ es,
                               float* __restrict__ ed, int n) {
  int w = (blockIdx.x * 256 + threadIdx.x) >> 6;
  int lane = threadIdx.x & 63;
  if (w >= n) return;
  float v0 = bf2f(h[(size_t)w * 128 + lane]);
  float v1 = bf2f(h[(size_t)w * 128 + 64 + lane]);
  float s0 = v0 * a_src[lane];
  float s1 = v1 * a_src[64 + lane];
  float d0 = v0 * a_dst[lane];
  float d1 = v1 * a_dst[64 + lane];
  for (int o = 32; o; o >>= 1) {
    s0 += __shfl_down(s0, o);
    s1 += __shfl_down(s1, o);
    d0 += __shfl_down(d0, o);
    d1 += __shfl_down(d1, o);
  }
  if (lane == 0) {
    es[w * 2] = s0; es[w * 2 + 1] = s1;
    ed[w * 2] = d0; ed[w * 2 + 1] = d1;
  }
}

__global__ void escore2_kernel(const uint16_t* __restrict__ h, const float* __restrict__ a_src,
                               const float* __restrict__ a_dst, float* __restrict__ es,
                               float* __restrict__ ed, int n) {
  int w = (blockIdx.x * 256 + threadIdx.x) >> 6;
  int lane = threadIdx.x & 63;
  if (w >= n) return;
  float v = bf2f(h[(size_t)w * 64 + lane]);
  float s = v * a_src[lane];
  float d = v * a_dst[lane];
  for (int o = 32; o; o >>= 1) {
    s += __shfl_down(s, o);
    d += __shfl_down(d, o);
  }
  if (lane == 0) { es[w] = s; ed[w] = d; }
}

// ---------------- layer-2 edge weights (edge-parallel, coalesced) -------------

__global__ void wprep2_kernel(const float* __restrict__ es, const float* __restrict__ ed,
                              const int* __restrict__ ssrc, const int* __restrict__ sdst,
                              float* __restrict__ wgt, int E2) {
  int e = blockIdx.x * 256 + threadIdx.x;
  if (e >= E2) return;
  int s = ssrc[e], d = sdst[e];
  wgt[e] = __expf(LRELU(es[s] + ed[d]));
}

// ---------------- aggregation (wave per dst node, raw wgts + in-reg denom) ----

__global__ void agg1_kernel(const uint32_t* __restrict__ hv, const float2* __restrict__ wgt,
                            const int* __restrict__ off, const int* __restrict__ ssrc,
                            const float* __restrict__ b, uint32_t* __restrict__ outb, int n) {
  int w = __builtin_amdgcn_readfirstlane((blockIdx.x * 256 + threadIdx.x) >> 6);
  int lane = threadIdx.x & 63;
  if (w >= n) return;
  bool hi = lane >= 32;  // head 1
  float ax = 0.f, ay = 0.f, den = 0.f;
  int e0 = off[w], e1 = off[w + 1];
  int e = e0;
  for (; e + 8 <= e1; e += 8) {
    int s[8];
    float2 wv[8];
    uint32_t g[8];
#pragma unroll
    for (int u = 0; u < 8; ++u) { s[u] = ssrc[e + u]; wv[u] = wgt[e + u]; }
#pragma unroll
    for (int u = 0; u < 8; ++u) g[u] = hv[(size_t)s[u] * 64 + lane];
#pragma unroll
    for (int u = 0; u < 8; ++u) {
      float a = hi ? wv[u].y : wv[u].x;
      den += a;
      ax = fmaf(a, __uint_as_float(g[u] << 16), ax);
      ay = fmaf(a, __uint_as_float(g[u] & 0xffff0000u), ay);
    }
  }
  for (; e + 4 <= e1; e += 4) {
    int s[4];
    float2 wv[4];
    uint32_t g[4];
#pragma unroll
    for (int u = 0; u < 4; ++u) { s[u] = ssrc[e + u]; wv[u] = wgt[e + u]; }
#pragma unroll
    for (int u = 0; u < 4; ++u) g[u] = hv[(size_t)s[u] * 64 + lane];
#pragma unroll
    for (int u = 0; u < 4; ++u) {
      float a = hi ? wv[u].y : wv[u].x;
      den += a;
      ax = fmaf(a, __uint_as_float(g[u] << 16), ax);
      ay = fmaf(a, __uint_as_float(g[u] & 0xffff0000u), ay);
    }
  }
  for (; e < e1; ++e) {
    int s = ssrc[e];
    float2 wv = wgt[e];
    uint32_t g = hv[(size_t)s * 64 + lane];
    float a = hi ? wv.y : wv.x;
    den += a;
    ax = fmaf(a, __uint_as_float(g << 16), ax);
    ay = fmaf(a, __uint_as_float(g & 0xffff0000u), ay);
  }
  float inv = 1.0f / den;
  float2 bb = reinterpret_cast<const float2*>(b)[lane];
  float o0 = fmaxf(fmaf(ax, inv, bb.x), 0.f);   // ReLU
  float o1 = fmaxf(fmaf(ay, inv, bb.y), 0.f);
  outb[(size_t)w * 64 + lane] = pack2bf(o0, o1);  // bf16 row of 128 for GEMM2
}

__global__ void agg2_kernel(const uint16_t* __restrict__ h, const float* __restrict__ wgt,
                            const int* __restrict__ off, const int* __restrict__ ssrc,
                            const float* __restrict__ b, float* __restrict__ out, int n) {
  int w = __builtin_amdgcn_readfirstlane((blockIdx.x * 256 + threadIdx.x) >> 6);
  int lane = threadIdx.x & 63;
  if (w >= n) return;
  float acc = 0.f, den = 0.f;
  int e0 = off[w], e1 = off[w + 1];
  int e = e0;
  for (; e + 8 <= e1; e += 8) {
    int s[8];
    float wv[8];
    uint16_t g[8];
#pragma unroll
    for (int u = 0; u < 8; ++u) { s[u] = ssrc[e + u]; wv[u] = wgt[e + u]; }
#pragma unroll
    for (int u = 0; u < 8; ++u) g[u] = h[(size_t)s[u] * 64 + lane];
#pragma unroll
    for (int u = 0; u < 8; ++u) { den += wv[u]; acc = fmaf(wv[u], bf2f(g[u]), acc); }
  }
  for (; e + 4 <= e1; e += 4) {
    int s[4];
    float wv[4];
    uint16_t g[4];
#pragma unroll
    for (int u = 0; u < 4; ++u) { s[u] = ssrc[e + u]; wv[u] = wgt[e + u]; }
#pragma unroll
    for (int u = 0; u < 4; ++u) g[u] = h[(size_t)s[u] * 64 + lane];
#pragma unroll
    for (int u = 0; u < 4; ++u) { den += wv[u]; acc = fmaf(wv[u], bf2f(g[u]), acc); }
  }
  for (; e < e1; ++e) {
    float wv = wgt[e];
    den += wv;
    acc = fmaf(wv, bf2f(h[(size_t)ssrc[e] * 64 + lane]), acc);
  }
  out[(size_t)w * 64 + lane] = acc / den + b[lane];    // no ReLU after layer 2
}

// ---------------- pooling + MLP ----------------

__global__ void pool_kernel(const float* __restrict__ x, const int* __restrict__ batch,
                            float* __restrict__ pooled, float* __restrict__ cnt, int n) {
  int w = (blockIdx.x * 256 + threadIdx.x) >> 6;
  int lane = threadIdx.x & 63;
  int n0 = w * 64;
  if (n0 >= n) return;
  int n1 = min(n, n0 + 64);
  float acc = 0.f;
  int cur = batch[n0];
  int run = 0;
  for (int i = n0; i < n1; ++i) {
    int g = batch[i];
    if (g != cur) {
      atomicAdd(&pooled[cur * 64 + lane], acc);
      if (lane == 0) atomicAdd(&cnt[cur], (float)run);
      acc = 0.f; run = 0; cur = g;
    }
    acc += x[(size_t)i * 64 + lane];
    ++run;
  }
  atomicAdd(&pooled[cur * 64 + lane], acc);
  if (lane == 0) atomicAdd(&cnt[cur], (float)run);
}

__global__ void mlp1_kernel(const float* __restrict__ pooled, const float* __restrict__ cnt,
                            const float* __restrict__ dw1, const float* __restrict__ db1,
                            float* __restrict__ z) {
  int g = blockIdx.x;
  int c = threadIdx.x;  // 64
  __shared__ float P[64];
  float inv = 1.0f / fmaxf(cnt[g], 1.0f);
  P[c] = pooled[g * 64 + c] * inv;
  __syncthreads();
  float s = db1[c];
#pragma unroll
  for (int k = 0; k < 64; ++k) s = fmaf(P[k], dw1[k * 64 + c], s);
  z[g * 64 + c] = fmaxf(s, 0.f);
}

__global__ void mlp2_kernel(const float* __restrict__ z, const float* __restrict__ dw2,
                            const float* __restrict__ db2, float* __restrict__ out) {
  int g = blockIdx.x;
  int o = threadIdx.x;  // 16
  __shared__ float Z[64];
  for (int i = o; i < 64; i += 16) Z[i] = z[g * 64 + i];
  __syncthreads();
  float s = db2[o];
#pragma unroll
  for (int c = 0; c < 64; ++c) s = fmaf(Z[c], dw2[c * 16 + o], s);
  out[g * 16 + o] = s;
}

// ---------------- launch ----------------

extern "C" void kernel_launch(void* const* d_in, const int* in_sizes, int n_in,
                              void* d_out, int out_size, void* d_ws, size_t ws_size,
                              hipStream_t stream) {
  const float* x      = (const float*)d_in[0];
  const int*   ei     = (const int*)d_in[1];
  const int*   batch  = (const int*)d_in[2];
  const float* W1     = (const float*)d_in[3];
  const float* a_src1 = (const float*)d_in[4];
  const float* a_dst1 = (const float*)d_in[5];
  const float* b1     = (const float*)d_in[6];
  const float* W2     = (const float*)d_in[7];
  const float* a_src2 = (const float*)d_in[8];
  const float* a_dst2 = (const float*)d_in[9];
  const float* b2     = (const float*)d_in[10];
  const float* dw1    = (const float*)d_in[11];
  const float* db1    = (const float*)d_in[12];
  const float* dw2    = (const float*)d_in[13];
  const float* db2    = (const float*)d_in[14];
  float* out = (float*)d_out;

  const int N = in_sizes[2];
  const int E = in_sizes[1] / 2;
  const int E2 = E + N;
  const int G = out_size / 16;

  // smallest shift with NB <= 256 (bucket = 1<<shift nodes, <= 1024 for LDS)
  int shift = 8;
  while ((N >> shift) >= 256) ++shift;
  const int NB = ((N - 1) >> shift) + 1;

  char* ws = (char*)d_ws;
  size_t o = 0;
  auto alloc = [&](size_t bytes) {
    void* p = ws + o;
    o = (o + bytes + 255) & ~(size_t)255;
    return p;
  };
  int*      off    = (int*)alloc((size_t)(N + 1) * 4);
  int*      bcnt   = (int*)alloc(512 * 4);
  int*      boff   = (int*)alloc(516 * 4);
  int*      bcur   = (int*)alloc(512 * 4);
  int2*     bpairs = (int2*)alloc((size_t)E2 * 8);
  int*      ssrc   = (int*)alloc((size_t)E2 * 4);
  int*      sdst   = (int*)alloc((size_t)E2 * 4);
  float*    es1    = (float*)alloc((size_t)N * 2 * 4);
  float*    ed1    = (float*)alloc((size_t)N * 2 * 4);
  float*    es2    = (float*)alloc((size_t)N * 4);
  float*    ed2    = (float*)alloc((size_t)N * 4);
  float2*   wgt1   = (float2*)alloc((size_t)E2 * 8);
  float*    wgt2   = (float*)alloc((size_t)E2 * 4);
  float*    pooled = (float*)alloc((size_t)G * 64 * 4);
  float*    cntf   = (float*)alloc((size_t)G * 4);
  float*    zbuf   = (float*)alloc((size_t)G * 64 * 4);
  uint16_t* xb     = (uint16_t*)alloc((size_t)N * 128 * 2);  // bf16 x
  uint16_t* wt1b   = (uint16_t*)alloc((size_t)128 * 128 * 2);
  uint16_t* wt2b   = (uint16_t*)alloc((size_t)64 * 128 * 2);
  uint16_t* hb1    = (uint16_t*)alloc((size_t)N * 128 * 2);  // bf16 h1
  uint16_t* hb2    = (uint16_t*)alloc((size_t)N * 64 * 2);   // bf16 h2
  uint32_t* out1b  = (uint32_t*)alloc((size_t)N * 64 * 4);   // bf16 out1 (packed)
  float*    out2   = (float*)alloc((size_t)N * 64 * 4);

  hipMemsetAsync(bcnt, 0, 512 * 4, stream);
  hipMemsetAsync(pooled, 0, (size_t)G * 64 * 4, stream);
  hipMemsetAsync(cntf, 0, (size_t)G * 4, stream);

  int gM = (N + 127) / 128;            // mfma gemm blocks (128 rows each)
  int gW = (N + 3) / 4;
  int gE2 = (E2 + 255) / 256;
  int gCH = (E2 + 2047) / 2048;

  // ---- converts (x, W^T) ----
  int total8 = (N * 128) / 8;
  cvt_x_kernel<<<(total8 + 255) / 256, 256, 0, stream>>>(x, xb, total8);
  cvt_wt_kernel<<<(128 * 128 + 255) / 256, 256, 0, stream>>>(W1, wt1b, 128, 128 * 128);
  cvt_wt_kernel<<<(64 * 128 + 255) / 256, 256, 0, stream>>>(W2, wt2b, 64, 64 * 128);

  // ---- layer-1 GEMM + scores (independent of CSR) ----
  gemm_mfma<128><<<gM, 256, 0, stream>>>(xb, wt1b, hb1, N);
  escore1_kernel<<<gW, 256, 0, stream>>>(hb1, a_src1, a_dst1, es1, ed1, N);

  // ---- CSR build ----
  bcount_kernel<<<512, 256, 0, stream>>>(ei, bcnt, E, E2, shift, NB);
  bscan_kernel<<<1, 512, 0, stream>>>(bcnt, boff, bcur, NB);
  bscatter_kernel<<<gCH, 256, 0, stream>>>(ei, bcur, bpairs, E, E2, shift, NB);
  bfinal_kernel<<<NB, 256, 0, stream>>>(bpairs, boff, off, ssrc, sdst,
                                        (const float2*)es1, (const float2*)ed1,
                                        wgt1, N, E2, shift, NB);

  // ---- layer 1 aggregation (emits bf16 rows for GEMM2) ----
  agg1_kernel<<<gW, 256, 0, stream>>>((const uint32_t*)hb1, wgt1, off, ssrc, b1, out1b, N);

  // ---- layer 2 ----
  gemm_mfma<64><<<gM, 256, 0, stream>>>((const uint16_t*)out1b, wt2b, hb2, N);
  escore2_kernel<<<gW, 256, 0, stream>>>(hb2, a_src2, a_dst2, es2, ed2, N);
  wprep2_kernel<<<gE2, 256, 0, stream>>>(es2, ed2, ssrc, sdst, wgt2, E2);
  agg2_kernel<<<gW, 256, 0, stream>>>(hb2, wgt2, off, ssrc, b2, out2, N);

  // ---- pool + MLP ----
  int nwPool = (N + 63) / 64;
  pool_kernel<<<(nwPool + 3) / 4, 256, 0, stream>>>(out2, batch, pooled, cntf, N);
  mlp1_kernel<<<G, 64, 0, stream>>>(pooled, cntf, dw1, db1, zbuf);
  mlp2_kernel<<<G, 16, 0, stream>>>(zbuf, dw2, db2, out);
}

// Round 7
// 450.533 us; speedup vs baseline: 1.7489x; 1.0486x over previous
//
#include <hip/hip_runtime.h>
#include <stdint.h>

// ---------------------------------------------------------------------------
// SpatialGNN: 2x GATConv (2 heads -> 1 head), mean-pool per graph, MLP.
// R7: bfinal v3 -- stage sorted edges in LDS, stream ssrc out coalesced
//     (kills 7x partial-line write amplification). sdst/wgt1/wgt2/wprep2
//     deleted: agg kernels compute softmax weights inline from es[src]
//     (wave-uniform scalar gather) + ed[dst] (wave constant).
// ---------------------------------------------------------------------------

#define LRELU(x) ((x) > 0.f ? (x) : 0.2f * (x))

typedef short bf8 __attribute__((ext_vector_type(8)));   // 8 bf16 (4 VGPR)
typedef float f32x4 __attribute__((ext_vector_type(4))); // 4 fp32 acc

__device__ __forceinline__ uint16_t f2bf(float f) {
  uint32_t u = __float_as_uint(f);
  u += 0x7fff + ((u >> 16) & 1);   // RNE
  return (uint16_t)(u >> 16);
}
__device__ __forceinline__ float bf2f(uint16_t b) {
  return __uint_as_float(((uint32_t)b) << 16);
}
__device__ __forceinline__ uint32_t pack2bf(float a, float b) {
  return (uint32_t)f2bf(a) | ((uint32_t)f2bf(b) << 16);
}

// ---------------- dtype converts ----------------

__global__ void cvt_x_kernel(const float* __restrict__ x, uint16_t* __restrict__ xb,
                             int total8) {
  int i = (blockIdx.x * 256 + threadIdx.x);
  if (i >= total8) return;
  const float4* p = reinterpret_cast<const float4*>(x + (size_t)i * 8);
  float4 v0 = p[0], v1 = p[1];
  uint4 o;
  o.x = pack2bf(v0.x, v0.y);
  o.y = pack2bf(v0.z, v0.w);
  o.z = pack2bf(v1.x, v1.y);
  o.w = pack2bf(v1.z, v1.w);
  *reinterpret_cast<uint4*>(xb + (size_t)i * 8) = o;
}

// W [K=128 x N] fp32 -> WT [N x 128] bf16
__global__ void cvt_wt_kernel(const float* __restrict__ W, uint16_t* __restrict__ WT,
                              int N, int total) {
  int idx = blockIdx.x * 256 + threadIdx.x;
  if (idx >= total) return;
  int n = idx >> 7, k = idx & 127;
  WT[idx] = f2bf(W[(size_t)k * N + n]);
}

// ---------------- bf16 MFMA GEMM: C[M x N](bf16) = A[M x 128] * W[128 x N] ---

template <int N>
__global__ __launch_bounds__(256) void gemm_mfma(const uint16_t* __restrict__ A,
                                                 const uint16_t* __restrict__ WT,
                                                 uint16_t* __restrict__ C, int M) {
  constexpr int CT = N / 16;           // col tiles
  int wave = threadIdx.x >> 6;
  int lane = threadIdx.x & 63;
  int m16 = lane & 15;
  int quad = lane >> 4;                // 0..3
  int row_base = blockIdx.x * 128 + wave * 32;
  if (row_base >= M) return;           // M % 32 == 0 -> whole-wave guard exact
  const uint16_t* Ar0 = A + (size_t)(row_base + m16) * 128;
  const uint16_t* Ar1 = Ar0 + (size_t)16 * 128;
  f32x4 acc[2][CT] = {};
#pragma unroll
  for (int ks = 0; ks < 4; ++ks) {
    int k0 = ks * 32 + quad * 8;
    bf8 a0 = *reinterpret_cast<const bf8*>(Ar0 + k0);
    bf8 a1 = *reinterpret_cast<const bf8*>(Ar1 + k0);
#pragma unroll
    for (int c = 0; c < CT; ++c) {
      bf8 b = *reinterpret_cast<const bf8*>(WT + (size_t)(c * 16 + m16) * 128 + k0);
      acc[0][c] = __builtin_amdgcn_mfma_f32_16x16x32_bf16(a0, b, acc[0][c], 0, 0, 0);
      acc[1][c] = __builtin_amdgcn_mfma_f32_16x16x32_bf16(a1, b, acc[1][c], 0, 0, 0);
    }
  }
  // C/D layout: col = lane&15, row = quad*4 + reg   [m89-verified]
#pragma unroll
  for (int r = 0; r < 2; ++r) {
#pragma unroll
    for (int c = 0; c < CT; ++c) {
#pragma unroll
      for (int reg = 0; reg < 4; ++reg) {
        int row = row_base + r * 16 + quad * 4 + reg;
        C[(size_t)row * N + c * 16 + m16] = f2bf(acc[r][c][reg]);
      }
    }
  }
}

// ---------------- CSR build, phase A: bucket by dst>>shift ----------------

__global__ void bcount_kernel(const int* __restrict__ ei, int* __restrict__ bcnt,
                              int E, int E2, int shift, int nb) {
  __shared__ int lh[1024];
  int t = threadIdx.x;
  for (int i = t; i < 1024; i += 256) lh[i] = 0;
  __syncthreads();
  for (int e = blockIdx.x * 256 + t; e < E2; e += gridDim.x * 256) {
    int d = (e < E) ? ei[E + e] : (e - E);
    atomicAdd(&lh[d >> shift], 1);
  }
  __syncthreads();
  for (int i = t; i < nb; i += 256) {
    int v = lh[i];
    if (v) atomicAdd(&bcnt[i], v);
  }
}

// parallel exclusive scan over nb (<=1024) bucket counts
__global__ __launch_bounds__(512) void bscan_kernel(const int* __restrict__ bcnt,
                                                    int* __restrict__ boff,
                                                    int* __restrict__ bcur, int nb) {
  __shared__ int s[512];
  int t = threadIdx.x;
  int v0 = (2 * t < nb) ? bcnt[2 * t] : 0;
  int v1 = (2 * t + 1 < nb) ? bcnt[2 * t + 1] : 0;
  int sum = v0 + v1;
  s[t] = sum;
  __syncthreads();
  for (int d = 1; d < 512; d <<= 1) {
    int x = (t >= d) ? s[t - d] : 0;
    __syncthreads();
    s[t] += x;
    __syncthreads();
  }
  int run = s[t] - sum;
  if (2 * t < nb) { boff[2 * t] = run; bcur[2 * t] = run; }
  run += v0;
  if (2 * t + 1 < nb) { boff[2 * t + 1] = run; bcur[2 * t + 1] = run; }
  if (t == 511) boff[nb] = s[511];
}

// Each block bins 4096 edges into bucket-grouped (src,dst) pair runs.
__global__ void bscatter_kernel(const int* __restrict__ ei, int* __restrict__ bcur,
                                int2* __restrict__ bpairs, int E, int E2, int shift,
                                int nb) {
  __shared__ int lh[1024];
  __shared__ int lb[1024];
  int t = threadIdx.x;
  for (int i = t; i < 1024; i += 256) lh[i] = 0;
  __syncthreads();
  int base = blockIdx.x * 4096;
  int src[16], dst[16], rk[16], bk[16];
#pragma unroll
  for (int u = 0; u < 16; ++u) {
    int e = base + u * 256 + t;
    if (e < E2) {
      int s, d;
      if (e < E) { s = ei[e]; d = ei[E + e]; } else { s = d = e - E; }
      src[u] = s; dst[u] = d; bk[u] = d >> shift;
      rk[u] = atomicAdd(&lh[bk[u]], 1);
    } else rk[u] = -1;
  }
  __syncthreads();
  for (int i = t; i < nb; i += 256) {
    int c = lh[i];
    lb[i] = c ? atomicAdd(&bcur[i], c) : 0;
  }
  __syncthreads();
#pragma unroll
  for (int u = 0; u < 16; ++u) {
    if (rk[u] >= 0) bpairs[lb[bk[u]] + rk[u]] = make_int2(src[u], dst[u]);
  }
}

// ---------------- CSR phase B: one block per bucket, LDS-staged --------------
// off[bucket] == boff[bucket]; node offsets = boff + local scan. Edges are
// sorted into LDS, then ssrc streamed out fully coalesced (no partial lines).

#define BF_CAP 3072   // staged edges per bucket (mean ~2230 at shift=7)

__global__ __launch_bounds__(256) void bfinal_kernel(
    const int2* __restrict__ bpairs, const int* __restrict__ boff,
    int* __restrict__ off, int* __restrict__ ssrc,
    int N, int E2, int shift, int NB) {
  __shared__ int hist[512];
  __shared__ int loff[512];
  __shared__ int ssc[256];
  __shared__ int lsrc[BF_CAP];
  int b = blockIdx.x;
  int t = threadIdx.x;
  int bsz = 1 << shift;                       // nodes per bucket (<=512)
  int node0 = b << shift;
  int e0 = boff[b], e1 = boff[b + 1];
  int cnt = e1 - e0;
  bool fast = (cnt <= BF_CAP);
  for (int i = t; i < bsz; i += 256) hist[i] = 0;
  __syncthreads();
  int2 pe[12];
  int ne = 0;
  if (fast) {
#pragma unroll
    for (int j = 0; j < 12; ++j) {
      int e = e0 + j * 256 + t;
      if (e < e1) { pe[j] = bpairs[e]; ne = j + 1; }
    }
    for (int j = 0; j < ne; ++j) atomicAdd(&hist[pe[j].y - node0], 1);
  } else {
    for (int e = e0 + t; e < e1; e += 256) atomicAdd(&hist[bpairs[e].y - node0], 1);
  }
  __syncthreads();
  // exclusive scan over bsz entries
  int per = (bsz + 255) >> 8;                 // 1 or 2
  int basei = t * per;
  int va[2] = {0, 0};
  int sum = 0;
#pragma unroll 2
  for (int j = 0; j < per; ++j) {
    if (basei + j < bsz) va[j] = hist[basei + j];
    sum += va[j];
  }
  ssc[t] = sum;
  __syncthreads();
  for (int d = 1; d < 256; d <<= 1) {
    int x = (t >= d) ? ssc[t - d] : 0;
    __syncthreads();
    ssc[t] += x;
    __syncthreads();
  }
  int run = ssc[t] - sum;
#pragma unroll 2
  for (int j = 0; j < per; ++j) {
    if (basei + j < bsz) { loff[basei + j] = run; run += va[j]; }
  }
  __syncthreads();
  // node offsets (coalesced)
  for (int i = t; i < bsz; i += 256) {
    int v = node0 + i;
    if (v < N) off[v] = e0 + loff[i];
  }
  if (b == NB - 1 && t == 0) off[N] = E2;
  // rank + scatter
  for (int i = t; i < bsz; i += 256) hist[i] = 0;
  __syncthreads();
  if (fast) {
    for (int j = 0; j < ne; ++j) {
      int ld = pe[j].y - node0;
      int r = atomicAdd(&hist[ld], 1);
      lsrc[loff[ld] + r] = pe[j].x;
    }
    __syncthreads();
    for (int i = t; i < cnt; i += 256) ssrc[e0 + i] = lsrc[i];  // coalesced
  } else {
    for (int e = e0 + t; e < e1; e += 256) {
      int2 p = bpairs[e];
      int ld = p.y - node0;
      int r = atomicAdd(&hist[ld], 1);
      ssrc[e0 + loff[ld] + r] = p.x;
    }
  }
}

// ---------------- attention scores (per-node dot products, bf16 h) ------------

__global__ void escore1_kernel(const uint16_t* __restrict__ h, const float* __restrict__ a_src,
                               const float* __restrict__ a_dst, float* __restrict__ es,
                               float* __restrict__ ed, int n) {
  int w = (blockIdx.x * 256 + threadIdx.x) >> 6;
  int lane = threadIdx.x & 63;
  if (w >= n) return;
  float v0 = bf2f(h[(size_t)w * 128 + lane]);
  float v1 = bf2f(h[(size_t)w * 128 + 64 + lane]);
  float s0 = v0 * a_src[lane];
  float s1 = v1 * a_src[64 + lane];
  float d0 = v0 * a_dst[lane];
  float d1 = v1 * a_dst[64 + lane];
  for (int o = 32; o; o >>= 1) {
    s0 += __shfl_down(s0, o);
    s1 += __shfl_down(s1, o);
    d0 += __shfl_down(d0, o);
    d1 += __shfl_down(d1, o);
  }
  if (lane == 0) {
    es[w * 2] = s0; es[w * 2 + 1] = s1;
    ed[w * 2] = d0; ed[w * 2 + 1] = d1;
  }
}

__global__ void escore2_kernel(const uint16_t* __restrict__ h, const float* __restrict__ a_src,
                               const float* __restrict__ a_dst, float* __restrict__ es,
                               float* __restrict__ ed, int n) {
  int w = (blockIdx.x * 256 + threadIdx.x) >> 6;
  int lane = threadIdx.x & 63;
  if (w >= n) return;
  float v = bf2f(h[(size_t)w * 64 + lane]);
  float s = v * a_src[lane];
  float d = v * a_dst[lane];
  for (int o = 32; o; o >>= 1) {
    s += __shfl_down(s, o);
    d += __shfl_down(d, o);
  }
  if (lane == 0) { es[w] = s; ed[w] = d; }
}

// ---------------- aggregation (wave per node; weights computed inline) --------
// es[src] is a wave-uniform scalar gather; ed[w] is a wave constant.

__global__ void agg1_kernel(const uint32_t* __restrict__ hv, const float2* __restrict__ es,
                            const float2* __restrict__ ed, const int* __restrict__ off,
                            const int* __restrict__ ssrc, const float* __restrict__ b,
                            uint32_t* __restrict__ outb, int n) {
  int w = __builtin_amdgcn_readfirstlane((blockIdx.x * 256 + threadIdx.x) >> 6);
  int lane = threadIdx.x & 63;
  if (w >= n) return;
  bool hi = lane >= 32;  // head 1
  float2 edw = ed[w];
  float edh = hi ? edw.y : edw.x;
  float ax = 0.f, ay = 0.f, den = 0.f;
  int e0 = off[w], e1 = off[w + 1];
  int e = e0;
  for (; e + 8 <= e1; e += 8) {
    int s[8];
    float2 ev[8];
    uint32_t g[8];
#pragma unroll
    for (int u = 0; u < 8; ++u) s[u] = ssrc[e + u];
#pragma unroll
    for (int u = 0; u < 8; ++u) { ev[u] = es[s[u]]; g[u] = hv[(size_t)s[u] * 64 + lane]; }
#pragma unroll
    for (int u = 0; u < 8; ++u) {
      float x = (hi ? ev[u].y : ev[u].x) + edh;
      float a = __expf(LRELU(x));
      den += a;
      ax = fmaf(a, __uint_as_float(g[u] << 16), ax);
      ay = fmaf(a, __uint_as_float(g[u] & 0xffff0000u), ay);
    }
  }
  for (; e + 4 <= e1; e += 4) {
    int s[4];
    float2 ev[4];
    uint32_t g[4];
#pragma unroll
    for (int u = 0; u < 4; ++u) s[u] = ssrc[e + u];
#pragma unroll
    for (int u = 0; u < 4; ++u) { ev[u] = es[s[u]]; g[u] = hv[(size_t)s[u] * 64 + lane]; }
#pragma unroll
    for (int u = 0; u < 4; ++u) {
      float x = (hi ? ev[u].y : ev[u].x) + edh;
      float a = __expf(LRELU(x));
      den += a;
      ax = fmaf(a, __uint_as_float(g[u] << 16), ax);
      ay = fmaf(a, __uint_as_float(g[u] & 0xffff0000u), ay);
    }
  }
  for (; e < e1; ++e) {
    int s = ssrc[e];
    float2 ev = es[s];
    uint32_t g = hv[(size_t)s * 64 + lane];
    float x = (hi ? ev.y : ev.x) + edh;
    float a = __expf(LRELU(x));
    den += a;
    ax = fmaf(a, __uint_as_float(g << 16), ax);
    ay = fmaf(a, __uint_as_float(g & 0xffff0000u), ay);
  }
  float inv = 1.0f / den;
  float2 bb = reinterpret_cast<const float2*>(b)[lane];
  float o0 = fmaxf(fmaf(ax, inv, bb.x), 0.f);   // ReLU
  float o1 = fmaxf(fmaf(ay, inv, bb.y), 0.f);
  outb[(size_t)w * 64 + lane] = pack2bf(o0, o1);  // bf16 row of 128 for GEMM2
}

__global__ void agg2_kernel(const uint16_t* __restrict__ h, const float* __restrict__ es,
                            const float* __restrict__ ed, const int* __restrict__ off,
                            const int* __restrict__ ssrc, const float* __restrict__ b,
                            float* __restrict__ out, int n) {
  int w = __builtin_amdgcn_readfirstlane((blockIdx.x * 256 + threadIdx.x) >> 6);
  int lane = threadIdx.x & 63;
  if (w >= n) return;
  float edw = ed[w];
  float acc = 0.f, den = 0.f;
  int e0 = off[w], e1 = off[w + 1];
  int e = e0;
  for (; e + 8 <= e1; e += 8) {
    int s[8];
    float evs[8];
    uint16_t g[8];
#pragma unroll
    for (int u = 0; u < 8; ++u) s[u] = ssrc[e + u];
#pragma unroll
    for (int u = 0; u < 8; ++u) { evs[u] = es[s[u]]; g[u] = h[(size_t)s[u] * 64 + lane]; }
#pragma unroll
    for (int u = 0; u < 8; ++u) {
      float a = __expf(LRELU(evs[u] + edw));
      den += a;
      acc = fmaf(a, bf2f(g[u]), acc);
    }
  }
  for (; e + 4 <= e1; e += 4) {
    int s[4];
    float evs[4];
    uint16_t g[4];
#pragma unroll
    for (int u = 0; u < 4; ++u) s[u] = ssrc[e + u];
#pragma unroll
    for (int u = 0; u < 4; ++u) { evs[u] = es[s[u]]; g[u] = h[(size_t)s[u] * 64 + lane]; }
#pragma unroll
    for (int u = 0; u < 4; ++u) {
      float a = __expf(LRELU(evs[u] + edw));
      den += a;
      acc = fmaf(a, bf2f(g[u]), acc);
    }
  }
  for (; e < e1; ++e) {
    int s = ssrc[e];
    float a = __expf(LRELU(es[s] + edw));
    den += a;
    acc = fmaf(a, bf2f(h[(size_t)s * 64 + lane]), acc);
  }
  out[(size_t)w * 64 + lane] = acc / den + b[lane];    // no ReLU after layer 2
}

// ---------------- pooling + MLP ----------------

__global__ void pool_kernel(const float* __restrict__ x, const int* __restrict__ batch,
                            float* __restrict__ pooled, float* __restrict__ cnt, int n) {
  int w = (blockIdx.x * 256 + threadIdx.x) >> 6;
  int lane = threadIdx.x & 63;
  int n0 = w * 64;
  if (n0 >= n) return;
  int n1 = min(n, n0 + 64);
  float acc = 0.f;
  int cur = batch[n0];
  int run = 0;
  for (int i = n0; i < n1; ++i) {
    int g = batch[i];
    if (g != cur) {
      atomicAdd(&pooled[cur * 64 + lane], acc);
      if (lane == 0) atomicAdd(&cnt[cur], (float)run);
      acc = 0.f; run = 0; cur = g;
    }
    acc += x[(size_t)i * 64 + lane];
    ++run;
  }
  atomicAdd(&pooled[cur * 64 + lane], acc);
  if (lane == 0) atomicAdd(&cnt[cur], (float)run);
}

__global__ void mlp1_kernel(const float* __restrict__ pooled, const float* __restrict__ cnt,
                            const float* __restrict__ dw1, const float* __restrict__ db1,
                            float* __restrict__ z) {
  int g = blockIdx.x;
  int c = threadIdx.x;  // 64
  __shared__ float P[64];
  float inv = 1.0f / fmaxf(cnt[g], 1.0f);
  P[c] = pooled[g * 64 + c] * inv;
  __syncthreads();
  float s = db1[c];
#pragma unroll
  for (int k = 0; k < 64; ++k) s = fmaf(P[k], dw1[k * 64 + c], s);
  z[g * 64 + c] = fmaxf(s, 0.f);
}

__global__ void mlp2_kernel(const float* __restrict__ z, const float* __restrict__ dw2,
                            const float* __restrict__ db2, float* __restrict__ out) {
  int g = blockIdx.x;
  int o = threadIdx.x;  // 16
  __shared__ float Z[64];
  for (int i = o; i < 64; i += 16) Z[i] = z[g * 64 + i];
  __syncthreads();
  float s = db2[o];
#pragma unroll
  for (int c = 0; c < 64; ++c) s = fmaf(Z[c], dw2[c * 16 + o], s);
  out[g * 16 + o] = s;
}

// ---------------- launch ----------------

extern "C" void kernel_launch(void* const* d_in, const int* in_sizes, int n_in,
                              void* d_out, int out_size, void* d_ws, size_t ws_size,
                              hipStream_t stream) {
  const float* x      = (const float*)d_in[0];
  const int*   ei     = (const int*)d_in[1];
  const int*   batch  = (const int*)d_in[2];
  const float* W1     = (const float*)d_in[3];
  const float* a_src1 = (const float*)d_in[4];
  const float* a_dst1 = (const float*)d_in[5];
  const float* b1     = (const float*)d_in[6];
  const float* W2     = (const float*)d_in[7];
  const float* a_src2 = (const float*)d_in[8];
  const float* a_dst2 = (const float*)d_in[9];
  const float* b2     = (const float*)d_in[10];
  const float* dw1    = (const float*)d_in[11];
  const float* db1    = (const float*)d_in[12];
  const float* dw2    = (const float*)d_in[13];
  const float* db2    = (const float*)d_in[14];
  float* out = (float*)d_out;

  const int N = in_sizes[2];
  const int E = in_sizes[1] / 2;
  const int E2 = E + N;
  const int G = out_size / 16;

  // bucket = 1<<shift nodes; need NB <= 1024 and bsz <= 512
  int shift = 7;
  while ((N >> shift) >= 1024) ++shift;
  const int NB = ((N - 1) >> shift) + 1;

  char* ws = (char*)d_ws;
  size_t o = 0;
  auto alloc = [&](size_t bytes) {
    void* p = ws + o;
    o = (o + bytes + 255) & ~(size_t)255;
    return p;
  };
  int*      off    = (int*)alloc((size_t)(N + 1) * 4);
  int*      bcnt   = (int*)alloc(1024 * 4);
  int*      boff   = (int*)alloc(1028 * 4);
  int*      bcur   = (int*)alloc(1024 * 4);
  int2*     bpairs = (int2*)alloc((size_t)E2 * 8);
  int*      ssrc   = (int*)alloc((size_t)E2 * 4);
  float*    es1    = (float*)alloc((size_t)N * 2 * 4);
  float*    ed1    = (float*)alloc((size_t)N * 2 * 4);
  float*    es2    = (float*)alloc((size_t)N * 4);
  float*    ed2    = (float*)alloc((size_t)N * 4);
  float*    pooled = (float*)alloc((size_t)G * 64 * 4);
  float*    cntf   = (float*)alloc((size_t)G * 4);
  float*    zbuf   = (float*)alloc((size_t)G * 64 * 4);
  uint16_t* xb     = (uint16_t*)alloc((size_t)N * 128 * 2);  // bf16 x
  uint16_t* wt1b   = (uint16_t*)alloc((size_t)128 * 128 * 2);
  uint16_t* wt2b   = (uint16_t*)alloc((size_t)64 * 128 * 2);
  uint16_t* hb1    = (uint16_t*)alloc((size_t)N * 128 * 2);  // bf16 h1
  uint16_t* hb2    = (uint16_t*)alloc((size_t)N * 64 * 2);   // bf16 h2
  uint32_t* out1b  = (uint32_t*)alloc((size_t)N * 64 * 4);   // bf16 out1 (packed)
  float*    out2   = (float*)alloc((size_t)N * 64 * 4);

  hipMemsetAsync(bcnt, 0, 1024 * 4, stream);
  hipMemsetAsync(pooled, 0, (size_t)G * 64 * 4, stream);
  hipMemsetAsync(cntf, 0, (size_t)G * 4, stream);

  int gM = (N + 127) / 128;            // mfma gemm blocks (128 rows each)
  int gW = (N + 3) / 4;
  int gCH = (E2 + 4095) / 4096;

  // ---- converts (x, W^T) ----
  int total8 = (N * 128) / 8;
  cvt_x_kernel<<<(total8 + 255) / 256, 256, 0, stream>>>(x, xb, total8);
  cvt_wt_kernel<<<(128 * 128 + 255) / 256, 256, 0, stream>>>(W1, wt1b, 128, 128 * 128);
  cvt_wt_kernel<<<(64 * 128 + 255) / 256, 256, 0, stream>>>(W2, wt2b, 64, 64 * 128);

  // ---- layer-1 GEMM + scores (independent of CSR) ----
  gemm_mfma<128><<<gM, 256, 0, stream>>>(xb, wt1b, hb1, N);
  escore1_kernel<<<gW, 256, 0, stream>>>(hb1, a_src1, a_dst1, es1, ed1, N);

  // ---- CSR build ----
  bcount_kernel<<<512, 256, 0, stream>>>(ei, bcnt, E, E2, shift, NB);
  bscan_kernel<<<1, 512, 0, stream>>>(bcnt, boff, bcur, NB);
  bscatter_kernel<<<gCH, 256, 0, stream>>>(ei, bcur, bpairs, E, E2, shift, NB);
  bfinal_kernel<<<NB, 256, 0, stream>>>(bpairs, boff, off, ssrc, N, E2, shift, NB);

  // ---- layer 1 aggregation (emits bf16 rows for GEMM2) ----
  agg1_kernel<<<gW, 256, 0, stream>>>((const uint32_t*)hb1, (const float2*)es1,
                                      (const float2*)ed1, off, ssrc, b1, out1b, N);

  // ---- layer 2 ----
  gemm_mfma<64><<<gM, 256, 0, stream>>>((const uint16_t*)out1b, wt2b, hb2, N);
  escore2_kernel<<<gW, 256, 0, stream>>>(hb2, a_src2, a_dst2, es2, ed2, N);
  agg2_kernel<<<gW, 256, 0, stream>>>(hb2, es2, ed2, off, ssrc, b2, out2, N);

  // ---- pool + MLP ----
  int nwPool = (N + 63) / 64;
  pool_kernel<<<(nwPool + 3) / 4, 256, 0, stream>>>(out2, batch, pooled, cntf, N);
  mlp1_kernel<<<G, 64, 0, stream>>>(pooled, cntf, dw1, db1, zbuf);
  mlp2_kernel<<<G, 16, 0, stream>>>(zbuf, dw2, db2, out);
}

// Round 8
// 427.901 us; speedup vs baseline: 1.8414x; 1.0529x over previous
//
#include <hip/hip_runtime.h>
#include <stdint.h>

// ---------------------------------------------------------------------------
// SpatialGNN: 2x GATConv (2 heads -> 1 head), mean-pool per graph, MLP.
// R8: agg kernels restructured to quarter-wave edge parallelism --
//     4 edges in flight per wave slot, 16B/lane uint4 gathers (agg1),
//     exp/lrelu computed by 16 lanes/edge instead of 64 (VALU /4),
//     cross-sub-wave merge via 2x shfl_xor. CSR build & MFMA GEMMs unchanged.
// ---------------------------------------------------------------------------

#define LRELU(x) ((x) > 0.f ? (x) : 0.2f * (x))

typedef short bf8 __attribute__((ext_vector_type(8)));   // 8 bf16 (4 VGPR)
typedef float f32x4 __attribute__((ext_vector_type(4))); // 4 fp32 acc

__device__ __forceinline__ uint16_t f2bf(float f) {
  uint32_t u = __float_as_uint(f);
  u += 0x7fff + ((u >> 16) & 1);   // RNE
  return (uint16_t)(u >> 16);
}
__device__ __forceinline__ float bf2f(uint16_t b) {
  return __uint_as_float(((uint32_t)b) << 16);
}
__device__ __forceinline__ uint32_t pack2bf(float a, float b) {
  return (uint32_t)f2bf(a) | ((uint32_t)f2bf(b) << 16);
}
__device__ __forceinline__ float bflo(uint32_t u) { return __uint_as_float(u << 16); }
__device__ __forceinline__ float bfhi(uint32_t u) { return __uint_as_float(u & 0xffff0000u); }

// ---------------- dtype converts ----------------

__global__ void cvt_x_kernel(const float* __restrict__ x, uint16_t* __restrict__ xb,
                             int total8) {
  int i = (blockIdx.x * 256 + threadIdx.x);
  if (i >= total8) return;
  const float4* p = reinterpret_cast<const float4*>(x + (size_t)i * 8);
  float4 v0 = p[0], v1 = p[1];
  uint4 o;
  o.x = pack2bf(v0.x, v0.y);
  o.y = pack2bf(v0.z, v0.w);
  o.z = pack2bf(v1.x, v1.y);
  o.w = pack2bf(v1.z, v1.w);
  *reinterpret_cast<uint4*>(xb + (size_t)i * 8) = o;
}

// W [K=128 x N] fp32 -> WT [N x 128] bf16
__global__ void cvt_wt_kernel(const float* __restrict__ W, uint16_t* __restrict__ WT,
                              int N, int total) {
  int idx = blockIdx.x * 256 + threadIdx.x;
  if (idx >= total) return;
  int n = idx >> 7, k = idx & 127;
  WT[idx] = f2bf(W[(size_t)k * N + n]);
}

// ---------------- bf16 MFMA GEMM: C[M x N](bf16) = A[M x 128] * W[128 x N] ---

template <int N>
__global__ __launch_bounds__(256) void gemm_mfma(const uint16_t* __restrict__ A,
                                                 const uint16_t* __restrict__ WT,
                                                 uint16_t* __restrict__ C, int M) {
  constexpr int CT = N / 16;           // col tiles
  int wave = threadIdx.x >> 6;
  int lane = threadIdx.x & 63;
  int m16 = lane & 15;
  int quad = lane >> 4;                // 0..3
  int row_base = blockIdx.x * 128 + wave * 32;
  if (row_base >= M) return;           // M % 32 == 0 -> whole-wave guard exact
  const uint16_t* Ar0 = A + (size_t)(row_base + m16) * 128;
  const uint16_t* Ar1 = Ar0 + (size_t)16 * 128;
  f32x4 acc[2][CT] = {};
#pragma unroll
  for (int ks = 0; ks < 4; ++ks) {
    int k0 = ks * 32 + quad * 8;
    bf8 a0 = *reinterpret_cast<const bf8*>(Ar0 + k0);
    bf8 a1 = *reinterpret_cast<const bf8*>(Ar1 + k0);
#pragma unroll
    for (int c = 0; c < CT; ++c) {
      bf8 b = *reinterpret_cast<const bf8*>(WT + (size_t)(c * 16 + m16) * 128 + k0);
      acc[0][c] = __builtin_amdgcn_mfma_f32_16x16x32_bf16(a0, b, acc[0][c], 0, 0, 0);
      acc[1][c] = __builtin_amdgcn_mfma_f32_16x16x32_bf16(a1, b, acc[1][c], 0, 0, 0);
    }
  }
  // C/D layout: col = lane&15, row = quad*4 + reg   [m89-verified]
#pragma unroll
  for (int r = 0; r < 2; ++r) {
#pragma unroll
    for (int c = 0; c < CT; ++c) {
#pragma unroll
      for (int reg = 0; reg < 4; ++reg) {
        int row = row_base + r * 16 + quad * 4 + reg;
        C[(size_t)row * N + c * 16 + m16] = f2bf(acc[r][c][reg]);
      }
    }
  }
}

// ---------------- CSR build, phase A: bucket by dst>>shift ----------------

__global__ void bcount_kernel(const int* __restrict__ ei, int* __restrict__ bcnt,
                              int E, int E2, int shift, int nb) {
  __shared__ int lh[1024];
  int t = threadIdx.x;
  for (int i = t; i < 1024; i += 256) lh[i] = 0;
  __syncthreads();
  for (int e = blockIdx.x * 256 + t; e < E2; e += gridDim.x * 256) {
    int d = (e < E) ? ei[E + e] : (e - E);
    atomicAdd(&lh[d >> shift], 1);
  }
  __syncthreads();
  for (int i = t; i < nb; i += 256) {
    int v = lh[i];
    if (v) atomicAdd(&bcnt[i], v);
  }
}

// parallel exclusive scan over nb (<=1024) bucket counts
__global__ __launch_bounds__(512) void bscan_kernel(const int* __restrict__ bcnt,
                                                    int* __restrict__ boff,
                                                    int* __restrict__ bcur, int nb) {
  __shared__ int s[512];
  int t = threadIdx.x;
  int v0 = (2 * t < nb) ? bcnt[2 * t] : 0;
  int v1 = (2 * t + 1 < nb) ? bcnt[2 * t + 1] : 0;
  int sum = v0 + v1;
  s[t] = sum;
  __syncthreads();
  for (int d = 1; d < 512; d <<= 1) {
    int x = (t >= d) ? s[t - d] : 0;
    __syncthreads();
    s[t] += x;
    __syncthreads();
  }
  int run = s[t] - sum;
  if (2 * t < nb) { boff[2 * t] = run; bcur[2 * t] = run; }
  run += v0;
  if (2 * t + 1 < nb) { boff[2 * t + 1] = run; bcur[2 * t + 1] = run; }
  if (t == 511) boff[nb] = s[511];
}

// Each block bins 4096 edges into bucket-grouped (src,dst) pair runs.
__global__ void bscatter_kernel(const int* __restrict__ ei, int* __restrict__ bcur,
                                int2* __restrict__ bpairs, int E, int E2, int shift,
                                int nb) {
  __shared__ int lh[1024];
  __shared__ int lb[1024];
  int t = threadIdx.x;
  for (int i = t; i < 1024; i += 256) lh[i] = 0;
  __syncthreads();
  int base = blockIdx.x * 4096;
  int src[16], dst[16], rk[16], bk[16];
#pragma unroll
  for (int u = 0; u < 16; ++u) {
    int e = base + u * 256 + t;
    if (e < E2) {
      int s, d;
      if (e < E) { s = ei[e]; d = ei[E + e]; } else { s = d = e - E; }
      src[u] = s; dst[u] = d; bk[u] = d >> shift;
      rk[u] = atomicAdd(&lh[bk[u]], 1);
    } else rk[u] = -1;
  }
  __syncthreads();
  for (int i = t; i < nb; i += 256) {
    int c = lh[i];
    lb[i] = c ? atomicAdd(&bcur[i], c) : 0;
  }
  __syncthreads();
#pragma unroll
  for (int u = 0; u < 16; ++u) {
    if (rk[u] >= 0) bpairs[lb[bk[u]] + rk[u]] = make_int2(src[u], dst[u]);
  }
}

// ---------------- CSR phase B: one block per bucket, LDS-staged --------------

#define BF_CAP 3072   // staged edges per bucket (mean ~2230 at shift=7)

__global__ __launch_bounds__(256) void bfinal_kernel(
    const int2* __restrict__ bpairs, const int* __restrict__ boff,
    int* __restrict__ off, int* __restrict__ ssrc,
    int N, int E2, int shift, int NB) {
  __shared__ int hist[512];
  __shared__ int loff[512];
  __shared__ int ssc[256];
  __shared__ int lsrc[BF_CAP];
  int b = blockIdx.x;
  int t = threadIdx.x;
  int bsz = 1 << shift;                       // nodes per bucket (<=512)
  int node0 = b << shift;
  int e0 = boff[b], e1 = boff[b + 1];
  int cnt = e1 - e0;
  bool fast = (cnt <= BF_CAP);
  for (int i = t; i < bsz; i += 256) hist[i] = 0;
  __syncthreads();
  int2 pe[12];
  int ne = 0;
  if (fast) {
#pragma unroll
    for (int j = 0; j < 12; ++j) {
      int e = e0 + j * 256 + t;
      if (e < e1) { pe[j] = bpairs[e]; ne = j + 1; }
    }
    for (int j = 0; j < ne; ++j) atomicAdd(&hist[pe[j].y - node0], 1);
  } else {
    for (int e = e0 + t; e < e1; e += 256) atomicAdd(&hist[bpairs[e].y - node0], 1);
  }
  __syncthreads();
  // exclusive scan over bsz entries
  int per = (bsz + 255) >> 8;                 // 1 or 2
  int basei = t * per;
  int va[2] = {0, 0};
  int sum = 0;
#pragma unroll 2
  for (int j = 0; j < per; ++j) {
    if (basei + j < bsz) va[j] = hist[basei + j];
    sum += va[j];
  }
  ssc[t] = sum;
  __syncthreads();
  for (int d = 1; d < 256; d <<= 1) {
    int x = (t >= d) ? ssc[t - d] : 0;
    __syncthreads();
    ssc[t] += x;
    __syncthreads();
  }
  int run = ssc[t] - sum;
#pragma unroll 2
  for (int j = 0; j < per; ++j) {
    if (basei + j < bsz) { loff[basei + j] = run; run += va[j]; }
  }
  __syncthreads();
  // node offsets (coalesced)
  for (int i = t; i < bsz; i += 256) {
    int v = node0 + i;
    if (v < N) off[v] = e0 + loff[i];
  }
  if (b == NB - 1 && t == 0) off[N] = E2;
  // rank + scatter
  for (int i = t; i < bsz; i += 256) hist[i] = 0;
  __syncthreads();
  if (fast) {
    for (int j = 0; j < ne; ++j) {
      int ld = pe[j].y - node0;
      int r = atomicAdd(&hist[ld], 1);
      lsrc[loff[ld] + r] = pe[j].x;
    }
    __syncthreads();
    for (int i = t; i < cnt; i += 256) ssrc[e0 + i] = lsrc[i];  // coalesced
  } else {
    for (int e = e0 + t; e < e1; e += 256) {
      int2 p = bpairs[e];
      int ld = p.y - node0;
      int r = atomicAdd(&hist[ld], 1);
      ssrc[e0 + loff[ld] + r] = p.x;
    }
  }
}

// ---------------- attention scores (per-node dot products, bf16 h) ------------

__global__ void escore1_kernel(const uint16_t* __restrict__ h, const float* __restrict__ a_src,
                               const float* __restrict__ a_dst, float* __restrict__ es,
                               float* __restrict__ ed, int n) {
  int w = (blockIdx.x * 256 + threadIdx.x) >> 6;
  int lane = threadIdx.x & 63;
  if (w >= n) return;
  float v0 = bf2f(h[(size_t)w * 128 + lane]);
  float v1 = bf2f(h[(size_t)w * 128 + 64 + lane]);
  float s0 = v0 * a_src[lane];
  float s1 = v1 * a_src[64 + lane];
  float d0 = v0 * a_dst[lane];
  float d1 = v1 * a_dst[64 + lane];
  for (int o = 32; o; o >>= 1) {
    s0 += __shfl_down(s0, o);
    s1 += __shfl_down(s1, o);
    d0 += __shfl_down(d0, o);
    d1 += __shfl_down(d1, o);
  }
  if (lane == 0) {
    es[w * 2] = s0; es[w * 2 + 1] = s1;
    ed[w * 2] = d0; ed[w * 2 + 1] = d1;
  }
}

__global__ void escore2_kernel(const uint16_t* __restrict__ h, const float* __restrict__ a_src,
                               const float* __restrict__ a_dst, float* __restrict__ es,
                               float* __restrict__ ed, int n) {
  int w = (blockIdx.x * 256 + threadIdx.x) >> 6;
  int lane = threadIdx.x & 63;
  if (w >= n) return;
  float v = bf2f(h[(size_t)w * 64 + lane]);
  float s = v * a_src[lane];
  float d = v * a_dst[lane];
  for (int o = 32; o; o >>= 1) {
    s += __shfl_down(s, o);
    d += __shfl_down(d, o);
  }
  if (lane == 0) { es[w] = s; ed[w] = d; }
}

// ---------------- aggregation: quarter-wave edge parallelism ------------------
// sub = lane>>4 owns edge (base+sub); q = lane&15 covers 8 channels (agg1,
// uint4 gather = 16B/lane) or 4 channels (agg2, uint2). exp computed by 16
// lanes/edge. Partial acc/den merged across sub-waves via shfl_xor(16,32).

__global__ void agg1_kernel(const uint4* __restrict__ h4, const float2* __restrict__ es,
                            const float2* __restrict__ ed, const int* __restrict__ off,
                            const int* __restrict__ ssrc, const float* __restrict__ b,
                            uint4* __restrict__ outb4, int n) {
  int w = __builtin_amdgcn_readfirstlane((blockIdx.x * 256 + threadIdx.x) >> 6);
  int lane = threadIdx.x & 63;
  if (w >= n) return;
  int sub = lane >> 4;         // edge slot 0..3
  int q = lane & 15;           // channel group: channels q*8 .. q*8+7
  bool hi = q >= 8;            // head 1 channels (64..127)
  float2 edw = ed[w];
  float edh = hi ? edw.y : edw.x;
  float acc[8] = {};
  float den = 0.f;
  int e0 = off[w], e1 = off[w + 1];
  int cnt = e1 - e0;
  int full = cnt & ~15;        // edges covered by fully-valid 16-edge iterations
  for (int base = e0; base < e0 + full; base += 16) {
    int s[4];
    float2 ev[4];
    uint4 g[4];
#pragma unroll
    for (int j = 0; j < 4; ++j) s[j] = ssrc[base + j * 4 + sub];
#pragma unroll
    for (int j = 0; j < 4; ++j) { ev[j] = es[s[j]]; g[j] = h4[(size_t)s[j] * 16 + q]; }
#pragma unroll
    for (int j = 0; j < 4; ++j) {
      float a = __expf(LRELU((hi ? ev[j].y : ev[j].x) + edh));
      den += a;
      acc[0] = fmaf(a, bflo(g[j].x), acc[0]); acc[1] = fmaf(a, bfhi(g[j].x), acc[1]);
      acc[2] = fmaf(a, bflo(g[j].y), acc[2]); acc[3] = fmaf(a, bfhi(g[j].y), acc[3]);
      acc[4] = fmaf(a, bflo(g[j].z), acc[4]); acc[5] = fmaf(a, bfhi(g[j].z), acc[5]);
      acc[6] = fmaf(a, bflo(g[j].w), acc[6]); acc[7] = fmaf(a, bfhi(g[j].w), acc[7]);
    }
  }
  for (int base = e0 + full; base < e1; base += 4) {
    int e = base + sub;
    if (e < e1) {
      int s = ssrc[e];
      float2 ev = es[s];
      uint4 g = h4[(size_t)s * 16 + q];
      float a = __expf(LRELU((hi ? ev.y : ev.x) + edh));
      den += a;
      acc[0] = fmaf(a, bflo(g.x), acc[0]); acc[1] = fmaf(a, bfhi(g.x), acc[1]);
      acc[2] = fmaf(a, bflo(g.y), acc[2]); acc[3] = fmaf(a, bfhi(g.y), acc[3]);
      acc[4] = fmaf(a, bflo(g.z), acc[4]); acc[5] = fmaf(a, bfhi(g.z), acc[5]);
      acc[6] = fmaf(a, bflo(g.w), acc[6]); acc[7] = fmaf(a, bfhi(g.w), acc[7]);
    }
  }
  // merge the 4 sub-waves (lanes differing in bits 4,5)
#pragma unroll
  for (int m = 16; m <= 32; m <<= 1) {
    den += __shfl_xor(den, m);
#pragma unroll
    for (int j = 0; j < 8; ++j) acc[j] += __shfl_xor(acc[j], m);
  }
  if (sub == 0) {
    float inv = 1.0f / den;
    float4 b0 = reinterpret_cast<const float4*>(b)[q * 2];
    float4 b1 = reinterpret_cast<const float4*>(b)[q * 2 + 1];
    float o0 = fmaxf(fmaf(acc[0], inv, b0.x), 0.f);
    float o1 = fmaxf(fmaf(acc[1], inv, b0.y), 0.f);
    float o2 = fmaxf(fmaf(acc[2], inv, b0.z), 0.f);
    float o3 = fmaxf(fmaf(acc[3], inv, b0.w), 0.f);
    float o4 = fmaxf(fmaf(acc[4], inv, b1.x), 0.f);
    float o5 = fmaxf(fmaf(acc[5], inv, b1.y), 0.f);
    float o6 = fmaxf(fmaf(acc[6], inv, b1.z), 0.f);
    float o7 = fmaxf(fmaf(acc[7], inv, b1.w), 0.f);
    uint4 o;
    o.x = pack2bf(o0, o1);
    o.y = pack2bf(o2, o3);
    o.z = pack2bf(o4, o5);
    o.w = pack2bf(o6, o7);
    outb4[(size_t)w * 16 + q] = o;   // bf16 row of 128 for GEMM2
  }
}

__global__ void agg2_kernel(const uint2* __restrict__ h2, const float* __restrict__ es,
                            const float* __restrict__ ed, const int* __restrict__ off,
                            const int* __restrict__ ssrc, const float* __restrict__ b,
                            float4* __restrict__ out4, int n) {
  int w = __builtin_amdgcn_readfirstlane((blockIdx.x * 256 + threadIdx.x) >> 6);
  int lane = threadIdx.x & 63;
  if (w >= n) return;
  int sub = lane >> 4;         // edge slot 0..3
  int q = lane & 15;           // channels q*4 .. q*4+3
  float edw = ed[w];
  float acc[4] = {};
  float den = 0.f;
  int e0 = off[w], e1 = off[w + 1];
  int cnt = e1 - e0;
  int full = cnt & ~15;
  for (int base = e0; base < e0 + full; base += 16) {
    int s[4];
    float evs[4];
    uint2 g[4];
#pragma unroll
    for (int j = 0; j < 4; ++j) s[j] = ssrc[base + j * 4 + sub];
#pragma unroll
    for (int j = 0; j < 4; ++j) { evs[j] = es[s[j]]; g[j] = h2[(size_t)s[j] * 16 + q]; }
#pragma unroll
    for (int j = 0; j < 4; ++j) {
      float a = __expf(LRELU(evs[j] + edw));
      den += a;
      acc[0] = fmaf(a, bflo(g[j].x), acc[0]); acc[1] = fmaf(a, bfhi(g[j].x), acc[1]);
      acc[2] = fmaf(a, bflo(g[j].y), acc[2]); acc[3] = fmaf(a, bfhi(g[j].y), acc[3]);
    }
  }
  for (int base = e0 + full; base < e1; base += 4) {
    int e = base + sub;
    if (e < e1) {
      int s = ssrc[e];
      uint2 g = h2[(size_t)s * 16 + q];
      float a = __expf(LRELU(es[s] + edw));
      den += a;
      acc[0] = fmaf(a, bflo(g.x), acc[0]); acc[1] = fmaf(a, bfhi(g.x), acc[1]);
      acc[2] = fmaf(a, bflo(g.y), acc[2]); acc[3] = fmaf(a, bfhi(g.y), acc[3]);
    }
  }
#pragma unroll
  for (int m = 16; m <= 32; m <<= 1) {
    den += __shfl_xor(den, m);
#pragma unroll
    for (int j = 0; j < 4; ++j) acc[j] += __shfl_xor(acc[j], m);
  }
  if (sub == 0) {
    float inv = 1.0f / den;
    float4 bb = reinterpret_cast<const float4*>(b)[q];
    float4 o;
    o.x = fmaf(acc[0], inv, bb.x);
    o.y = fmaf(acc[1], inv, bb.y);
    o.z = fmaf(acc[2], inv, bb.z);
    o.w = fmaf(acc[3], inv, bb.w);
    out4[(size_t)w * 16 + q] = o;    // fp32 row of 64; no ReLU after layer 2
  }
}

// ---------------- pooling + MLP ----------------

__global__ void pool_kernel(const float* __restrict__ x, const int* __restrict__ batch,
                            float* __restrict__ pooled, float* __restrict__ cnt, int n) {
  int w = (blockIdx.x * 256 + threadIdx.x) >> 6;
  int lane = threadIdx.x & 63;
  int n0 = w * 64;
  if (n0 >= n) return;
  int n1 = min(n, n0 + 64);
  float acc = 0.f;
  int cur = batch[n0];
  int run = 0;
  for (int i = n0; i < n1; ++i) {
    int g = batch[i];
    if (g != cur) {
      atomicAdd(&pooled[cur * 64 + lane], acc);
      if (lane == 0) atomicAdd(&cnt[cur], (float)run);
      acc = 0.f; run = 0; cur = g;
    }
    acc += x[(size_t)i * 64 + lane];
    ++run;
  }
  atomicAdd(&pooled[cur * 64 + lane], acc);
  if (lane == 0) atomicAdd(&cnt[cur], (float)run);
}

__global__ void mlp1_kernel(const float* __restrict__ pooled, const float* __restrict__ cnt,
                            const float* __restrict__ dw1, const float* __restrict__ db1,
                            float* __restrict__ z) {
  int g = blockIdx.x;
  int c = threadIdx.x;  // 64
  __shared__ float P[64];
  float inv = 1.0f / fmaxf(cnt[g], 1.0f);
  P[c] = pooled[g * 64 + c] * inv;
  __syncthreads();
  float s = db1[c];
#pragma unroll
  for (int k = 0; k < 64; ++k) s = fmaf(P[k], dw1[k * 64 + c], s);
  z[g * 64 + c] = fmaxf(s, 0.f);
}

__global__ void mlp2_kernel(const float* __restrict__ z, const float* __restrict__ dw2,
                            const float* __restrict__ db2, float* __restrict__ out) {
  int g = blockIdx.x;
  int o = threadIdx.x;  // 16
  __shared__ float Z[64];
  for (int i = o; i < 64; i += 16) Z[i] = z[g * 64 + i];
  __syncthreads();
  float s = db2[o];
#pragma unroll
  for (int c = 0; c < 64; ++c) s = fmaf(Z[c], dw2[c * 16 + o], s);
  out[g * 16 + o] = s;
}

// ---------------- launch ----------------

extern "C" void kernel_launch(void* const* d_in, const int* in_sizes, int n_in,
                              void* d_out, int out_size, void* d_ws, size_t ws_size,
                              hipStream_t stream) {
  const float* x      = (const float*)d_in[0];
  const int*   ei     = (const int*)d_in[1];
  const int*   batch  = (const int*)d_in[2];
  const float* W1     = (const float*)d_in[3];
  const float* a_src1 = (const float*)d_in[4];
  const float* a_dst1 = (const float*)d_in[5];
  const float* b1     = (const float*)d_in[6];
  const float* W2     = (const float*)d_in[7];
  const float* a_src2 = (const float*)d_in[8];
  const float* a_dst2 = (const float*)d_in[9];
  const float* b2     = (const float*)d_in[10];
  const float* dw1    = (const float*)d_in[11];
  const float* db1    = (const float*)d_in[12];
  const float* dw2    = (const float*)d_in[13];
  const float* db2    = (const float*)d_in[14];
  float* out = (float*)d_out;

  const int N = in_sizes[2];
  const int E = in_sizes[1] / 2;
  const int E2 = E + N;
  const int G = out_size / 16;

  // bucket = 1<<shift nodes; need NB <= 1024 and bsz <= 512
  int shift = 7;
  while ((N >> shift) >= 1024) ++shift;
  const int NB = ((N - 1) >> shift) + 1;

  char* ws = (char*)d_ws;
  size_t o = 0;
  auto alloc = [&](size_t bytes) {
    void* p = ws + o;
    o = (o + bytes + 255) & ~(size_t)255;
    return p;
  };
  int*      off    = (int*)alloc((size_t)(N + 1) * 4);
  int*      bcnt   = (int*)alloc(1024 * 4);
  int*      boff   = (int*)alloc(1028 * 4);
  int*      bcur   = (int*)alloc(1024 * 4);
  int2*     bpairs = (int2*)alloc((size_t)E2 * 8);
  int*      ssrc   = (int*)alloc((size_t)E2 * 4);
  float*    es1    = (float*)alloc((size_t)N * 2 * 4);
  float*    ed1    = (float*)alloc((size_t)N * 2 * 4);
  float*    es2    = (float*)alloc((size_t)N * 4);
  float*    ed2    = (float*)alloc((size_t)N * 4);
  float*    pooled = (float*)alloc((size_t)G * 64 * 4);
  float*    cntf   = (float*)alloc((size_t)G * 4);
  float*    zbuf   = (float*)alloc((size_t)G * 64 * 4);
  uint16_t* xb     = (uint16_t*)alloc((size_t)N * 128 * 2);  // bf16 x
  uint16_t* wt1b   = (uint16_t*)alloc((size_t)128 * 128 * 2);
  uint16_t* wt2b   = (uint16_t*)alloc((size_t)64 * 128 * 2);
  uint16_t* hb1    = (uint16_t*)alloc((size_t)N * 128 * 2);  // bf16 h1
  uint16_t* hb2    = (uint16_t*)alloc((size_t)N * 64 * 2);   // bf16 h2
  uint32_t* out1b  = (uint32_t*)alloc((size_t)N * 64 * 4);   // bf16 out1 (packed)
  float*    out2   = (float*)alloc((size_t)N * 64 * 4);

  hipMemsetAsync(bcnt, 0, 1024 * 4, stream);
  hipMemsetAsync(pooled, 0, (size_t)G * 64 * 4, stream);
  hipMemsetAsync(cntf, 0, (size_t)G * 4, stream);

  int gM = (N + 127) / 128;            // mfma gemm blocks (128 rows each)
  int gW = (N + 3) / 4;
  int gCH = (E2 + 4095) / 4096;

  // ---- converts (x, W^T) ----
  int total8 = (N * 128) / 8;
  cvt_x_kernel<<<(total8 + 255) / 256, 256, 0, stream>>>(x, xb, total8);
  cvt_wt_kernel<<<(128 * 128 + 255) / 256, 256, 0, stream>>>(W1, wt1b, 128, 128 * 128);
  cvt_wt_kernel<<<(64 * 128 + 255) / 256, 256, 0, stream>>>(W2, wt2b, 64, 64 * 128);

  // ---- layer-1 GEMM + scores (independent of CSR) ----
  gemm_mfma<128><<<gM, 256, 0, stream>>>(xb, wt1b, hb1, N);
  escore1_kernel<<<gW, 256, 0, stream>>>(hb1, a_src1, a_dst1, es1, ed1, N);

  // ---- CSR build ----
  bcount_kernel<<<512, 256, 0, stream>>>(ei, bcnt, E, E2, shift, NB);
  bscan_kernel<<<1, 512, 0, stream>>>(bcnt, boff, bcur, NB);
  bscatter_kernel<<<gCH, 256, 0, stream>>>(ei, bcur, bpairs, E, E2, shift, NB);
  bfinal_kernel<<<NB, 256, 0, stream>>>(bpairs, boff, off, ssrc, N, E2, shift, NB);

  // ---- layer 1 aggregation (emits bf16 rows for GEMM2) ----
  agg1_kernel<<<gW, 256, 0, stream>>>((const uint4*)hb1, (const float2*)es1,
                                      (const float2*)ed1, off, ssrc, b1,
                                      (uint4*)out1b, N);

  // ---- layer 2 ----
  gemm_mfma<64><<<gM, 256, 0, stream>>>((const uint16_t*)out1b, wt2b, hb2, N);
  escore2_kernel<<<gW, 256, 0, stream>>>(hb2, a_src2, a_dst2, es2, ed2, N);
  agg2_kernel<<<gW, 256, 0, stream>>>((const uint2*)hb2, es2, ed2, off, ssrc, b2,
                                      (float4*)out2, N);

  // ---- pool + MLP ----
  int nwPool = (N + 63) / 64;
  pool_kernel<<<(nwPool + 3) / 4, 256, 0, stream>>>(out2, batch, pooled, cntf, N);
  mlp1_kernel<<<G, 64, 0, stream>>>(pooled, cntf, dw1, db1, zbuf);
  mlp2_kernel<<<G, 16, 0, stream>>>(zbuf, dw2, db2, out);
}